// Round 6
// baseline (574.735 us; speedup 1.0000x reference)
//
#include <hip/hip_runtime.h>
#include <hip/hip_fp16.h>
#include <stdint.h>

typedef unsigned short u16;
typedef unsigned int u32;
typedef short bf16x8 __attribute__((ext_vector_type(8)));
typedef _Float16 half8 __attribute__((ext_vector_type(8)));
typedef float f32x4 __attribute__((ext_vector_type(4)));

__device__ __forceinline__ float bf2f(u16 v) { return __uint_as_float(((u32)v) << 16); }

__device__ __forceinline__ u16 f2bf(float a) {
  u32 u = __float_as_uint(a); u += 0x7FFFu + ((u >> 16) & 1u); return (u16)(u >> 16);
}

__device__ __forceinline__ u32 packbf2(float a, float b) {
  u32 ua = __float_as_uint(a); ua += 0x7FFFu + ((ua >> 16) & 1u);
  u32 ub = __float_as_uint(b); ub += 0x7FFFu + ((ub >> 16) & 1u);
  return (ua >> 16) | (ub & 0xFFFF0000u);
}

__device__ __forceinline__ u32 packh2(float a, float b) {
  return (u32)__half_as_ushort(__float2half(a)) |
         ((u32)__half_as_ushort(__float2half(b)) << 16);
}

__device__ __forceinline__ float inval(const void* p, int idx, int isf) {
  return isf ? ((const float*)p)[idx] : bf2f(((const u16*)p)[idx]);
}

// ---------------------------------------------------------------------------
// Detect input dtype: flag=1 -> fp32 inputs (verified r3/r4 on this dataset).
// ---------------------------------------------------------------------------
__global__ void detect_kernel(const u16* __restrict__ w1raw, int* __restrict__ flag)
{
  int lane = threadIdx.x & 63;
  float m = 0.f;
  #pragma unroll
  for (int j = 0; j < 2; ++j) {
    float v = fabsf(bf2f(w1raw[lane + j * 64]));
    if (!(v < 1e6f)) v = 1e30f;
    m = fmaxf(m, v);
  }
  #pragma unroll
  for (int off = 32; off; off >>= 1) m = fmaxf(m, __shfl_xor(m, off));
  if (lane == 0) *flag = (m > 1e6f) ? 1 : 0;
}

// ---------------------------------------------------------------------------
// Split ingest: row 256 -> 768 bf16 cols. lo_pos=1: [hi|lo|hi]; 2: [hi|hi|lo].
// ---------------------------------------------------------------------------
__global__ __launch_bounds__(256) void split_kernel(
    const void* __restrict__ src, u16* __restrict__ dst,
    const int* __restrict__ flag, int n4, int lo_pos)
{
  int i = blockIdx.x * 256 + threadIdx.x;
  if (i >= n4) return;
  int row = i >> 6, g = i & 63;
  float v[4];
  if (*flag) {
    float4 t = ((const float4*)src)[i];
    v[0] = t.x; v[1] = t.y; v[2] = t.z; v[3] = t.w;
  } else {
    uint2 t = ((const uint2*)src)[i];
    const u16* p = (const u16*)&t;
    v[0] = bf2f(p[0]); v[1] = bf2f(p[1]); v[2] = bf2f(p[2]); v[3] = bf2f(p[3]);
  }
  u16 hi[4]; float lo[4];
  #pragma unroll
  for (int j = 0; j < 4; ++j) { hi[j] = f2bf(v[j]); lo[j] = v[j] - bf2f(hi[j]); }
  u32 hw0 = (u32)hi[0] | ((u32)hi[1] << 16);
  u32 hw1 = (u32)hi[2] | ((u32)hi[3] << 16);
  u32 lw0 = packbf2(lo[0], lo[1]);
  u32 lw1 = packbf2(lo[2], lo[3]);
  u32* base = (u32*)(dst + (size_t)row * 768);
  int c = g * 2;
  base[c] = hw0; base[c + 1] = hw1;
  if (lo_pos == 1) {
    base[128 + c] = lw0; base[128 + c + 1] = lw1;
    base[256 + c] = hw0; base[256 + c + 1] = hw1;
  } else {
    base[128 + c] = hw0; base[128 + c + 1] = hw1;
    base[256 + c] = lw0; base[256 + c + 1] = lw1;
  }
}

// ---------------------------------------------------------------------------
// Kernel 1: h = x @ W1^T + b1 via split-bf16 (K=768), fp32 out + sum/sumsq.
// Tile 128n x 64o, grid (32,8).
// ---------------------------------------------------------------------------
#define L1_LD 136
__global__ __launch_bounds__(256) void l1_kernel(
    const u16* __restrict__ xs, const u16* __restrict__ w1s, const void* __restrict__ b1,
    const int* __restrict__ flag, float* __restrict__ H, float2* __restrict__ PT)
{
  __shared__ u16 sA[128 * L1_LD];
  __shared__ u16 sB[64 * L1_LD];
  __shared__ float redbuf[8];
  const int n0 = blockIdx.x * 128, o0 = blockIdx.y * 64;
  const int t = threadIdx.x, wave = t >> 6, lane = t & 63, quad = lane >> 4, l16 = lane & 15;
  const int isf = *flag;
  f32x4 acc[2][4] = {};
  for (int ks = 0; ks < 768; ks += 128) {
    #pragma unroll
    for (int r = 0; r < 8; ++r) {
      int idx = t + r * 256;
      int row = idx >> 4, col = idx & 15;
      const uint4* src = (const uint4*)(xs + (size_t)(n0 + row) * 768 + ks) + col;
      *(uint4*)&sA[row * L1_LD + col * 8] = *src;
    }
    #pragma unroll
    for (int r = 0; r < 4; ++r) {
      int idx = t + r * 256;
      int row = idx >> 4, col = idx & 15;
      const uint4* src = (const uint4*)(w1s + (size_t)(o0 + row) * 768 + ks) + col;
      *(uint4*)&sB[row * L1_LD + col * 8] = *src;
    }
    __syncthreads();
    #pragma unroll
    for (int kk = 0; kk < 128; kk += 32) {
      bf16x8 bfr[4];
      #pragma unroll
      for (int fo = 0; fo < 4; ++fo)
        bfr[fo] = *(const bf16x8*)&sB[(fo * 16 + l16) * L1_LD + kk + quad * 8];
      #pragma unroll
      for (int fm = 0; fm < 2; ++fm) {
        bf16x8 av = *(const bf16x8*)&sA[(wave * 32 + fm * 16 + l16) * L1_LD + kk + quad * 8];
        #pragma unroll
        for (int fo = 0; fo < 4; ++fo)
          acc[fm][fo] = __builtin_amdgcn_mfma_f32_16x16x32_bf16(av, bfr[fo], acc[fm][fo], 0, 0, 0);
      }
    }
    __syncthreads();
  }
  float s = 0.f, sq = 0.f;
  #pragma unroll
  for (int fm = 0; fm < 2; ++fm)
  #pragma unroll
  for (int fo = 0; fo < 4; ++fo) {
    int o = o0 + fo * 16 + l16;
    float bias = inval(b1, o, isf);
    #pragma unroll
    for (int r = 0; r < 4; ++r) {
      int n = n0 + wave * 32 + fm * 16 + quad * 4 + r;
      float h = acc[fm][fo][r] + bias;
      H[(size_t)n * 512 + o] = h;
      s += h; sq += h * h;
    }
  }
  #pragma unroll
  for (int off = 32; off; off >>= 1) { s += __shfl_down(s, off); sq += __shfl_down(sq, off); }
  if (lane == 0) { redbuf[wave] = s; redbuf[4 + wave] = sq; }
  __syncthreads();
  if (t == 0) {
    float S = redbuf[0] + redbuf[1] + redbuf[2] + redbuf[3];
    float Q = redbuf[4] + redbuf[5] + redbuf[6] + redbuf[7];
    PT[blockIdx.y * 32 + blockIdx.x] = make_float2(S, Q);
  }
}

// ---------------------------------------------------------------------------
// Kernel 2: reduce 256 partials -> mean, rsqrt(var+eps)
// ---------------------------------------------------------------------------
__global__ __launch_bounds__(256) void red_kernel(const float2* __restrict__ PT, float* __restrict__ ST)
{
  __shared__ float sa[4], sb[4];
  const int t = threadIdx.x;
  float2 p = PT[t];
  float s = p.x, q = p.y;
  #pragma unroll
  for (int off = 32; off; off >>= 1) { s += __shfl_down(s, off); q += __shfl_down(q, off); }
  if ((t & 63) == 0) { sa[t >> 6] = s; sb[t >> 6] = q; }
  __syncthreads();
  if (t == 0) {
    float S = sa[0] + sa[1] + sa[2] + sa[3];
    float Q = sb[0] + sb[1] + sb[2] + sb[3];
    const float N = 4096.f * 512.f;
    float mean = S / N;
    float var = Q / N - mean * mean;
    ST[0] = mean;
    ST[1] = rsqrtf(var + 1e-5f);
  }
}

// ---------------------------------------------------------------------------
// Prep: reorder coeffs to K-interleaved fp16 rows.
// ---------------------------------------------------------------------------
__global__ __launch_bounds__(256) void prep2_kernel(
    const void* __restrict__ c2, u16* __restrict__ w2f, const int* __restrict__ flag)
{
  int u = blockIdx.x * 256 + threadIdx.x;  // 512*512
  int o = u >> 9, i = u & 511;
  u32* d = (u32*)(w2f + (size_t)o * 16384 + i * 32);
  if (*flag) {
    const float4* f0 = (const float4*)((const float*)c2 + ((size_t)o * 512 + i) * 16);
    const float4* f1 = (const float4*)((const float*)c2 + (size_t)512 * 512 * 16 + ((size_t)o * 512 + i) * 16);
    #pragma unroll
    for (int j = 0; j < 4; ++j) { float4 v = f0[j]; d[2*j] = packh2(v.x, v.y); d[2*j+1] = packh2(v.z, v.w); }
    #pragma unroll
    for (int j = 0; j < 4; ++j) { float4 v = f1[j]; d[8+2*j] = packh2(v.x, v.y); d[8+2*j+1] = packh2(v.z, v.w); }
  } else {
    const u16* s0 = (const u16*)c2 + ((size_t)o * 512 + i) * 16;
    const u16* s1 = (const u16*)c2 + (size_t)512 * 512 * 16 + ((size_t)o * 512 + i) * 16;
    #pragma unroll
    for (int j = 0; j < 8; ++j) d[j]   = packh2(bf2f(s0[2*j]), bf2f(s0[2*j+1]));
    #pragma unroll
    for (int j = 0; j < 8; ++j) d[8+j] = packh2(bf2f(s1[2*j]), bf2f(s1[2*j+1]));
  }
}

__global__ __launch_bounds__(256) void prep3_kernel(
    const void* __restrict__ c3, u16* __restrict__ w3f, const int* __restrict__ flag)
{
  int u = blockIdx.x * 256 + threadIdx.x;  // 256*512
  int o = u >> 9, i = u & 511;
  u32* d = (u32*)(w3f + (size_t)o * 8192 + i * 16);
  if (*flag) {
    const float4* f0 = (const float4*)((const float*)c3 + ((size_t)o * 512 + i) * 8);
    const float4* f1 = (const float4*)((const float*)c3 + (size_t)256 * 512 * 8 + ((size_t)o * 512 + i) * 8);
    #pragma unroll
    for (int j = 0; j < 2; ++j) { float4 v = f0[j]; d[2*j] = packh2(v.x, v.y); d[2*j+1] = packh2(v.z, v.w); }
    #pragma unroll
    for (int j = 0; j < 2; ++j) { float4 v = f1[j]; d[4+2*j] = packh2(v.x, v.y); d[4+2*j+1] = packh2(v.z, v.w); }
  } else {
    const u16* s0 = (const u16*)c3 + ((size_t)o * 512 + i) * 8;
    const u16* s1 = (const u16*)c3 + (size_t)256 * 512 * 8 + ((size_t)o * 512 + i) * 8;
    #pragma unroll
    for (int j = 0; j < 4; ++j) d[j]   = packh2(bf2f(s0[2*j]), bf2f(s0[2*j+1]));
    #pragma unroll
    for (int j = 0; j < 4; ++j) d[4+j] = packh2(bf2f(s1[2*j]), bf2f(s1[2*j+1]));
  }
}

// ---------------------------------------------------------------------------
// Kernel 3 v3: fused BN+ReLU+basis + fp16 GEMM, split-K (kz=2 or 3) partials,
// register-prefetch pipeline (next step's B/H loads overlap MFMA phase).
// Tile 64n x 128o. Grid (64,4,kz). LDS 52224 B -> 3 blocks/CU.
// ---------------------------------------------------------------------------
#define K2_LD 136
__global__ __launch_bounds__(256) void kan2_kernel(
    const float* __restrict__ H, const u16* __restrict__ w2f,
    const void* __restrict__ gammap, const void* __restrict__ betap,
    const int* __restrict__ flag, const float* __restrict__ ST,
    float* __restrict__ P, int kzT)
{
  __shared__ u16 sA[64 * K2_LD];
  __shared__ u16 sB[128 * K2_LD];
  const int n0 = blockIdx.x * 64, o0 = blockIdx.y * 128, kz = blockIdx.z;
  const int t = threadIdx.x, wave = t >> 6, lane = t & 63, quad = lane >> 4, l16 = lane & 15;
  const int wm = (wave & 1) * 32, wo = (wave >> 1) * 64;
  const int isf = *flag;
  const float mean = ST[0];
  const float gs = inval(gammap, 0, isf) * ST[1];
  const float beta = inval(betap, 0, isf);
  const int am = t >> 2, ai = t & 3;
  int i0, nst;
  if (kzT == 3) { i0 = (kz == 0) ? 0 : (kz == 1) ? 172 : 344; nst = (kz < 2) ? 43 : 42; }
  else          { i0 = kz * 256; nst = 64; }
  // B staging map: thread covers uint4 (row=idx>>4, col=idx&15), 8 per thread
  const int brow = t >> 4, bcol = t & 15;
  f32x4 acc[2][4] = {};
  uint4 pb[8]; float ph;
  // prologue: issue step-0 loads
  #pragma unroll
  for (int r = 0; r < 8; ++r)
    pb[r] = *((const uint4*)(w2f + (size_t)(o0 + brow + r * 16) * 16384 + (size_t)i0 * 32) + bcol);
  ph = H[(size_t)(n0 + am) * 512 + i0 + ai];
  for (int s = 0; s < nst; ++s) {
    const int ib = i0 + s * 4;
    // trig from prefetched h
    float a = fmaxf((ph - mean) * gs + beta, 0.f);
    float s1, c1; __sincosf(a, &s1, &c1);
    float cg[16], sg[16];
    cg[0] = c1; sg[0] = s1;
    #pragma unroll
    for (int g = 1; g < 16; ++g) {
      cg[g] = cg[g-1] * c1 - sg[g-1] * s1;
      sg[g] = sg[g-1] * c1 + cg[g-1] * s1;
    }
    u32 pk[16];
    #pragma unroll
    for (int j = 0; j < 8; ++j) pk[j] = packh2(cg[2*j], cg[2*j+1]);
    #pragma unroll
    for (int j = 0; j < 8; ++j) pk[8+j] = packh2(sg[2*j], sg[2*j+1]);
    // LDS writes (b128)
    #pragma unroll
    for (int r = 0; r < 8; ++r)
      *(uint4*)&sB[(brow + r * 16) * K2_LD + bcol * 8] = pb[r];
    {
      uint4* dst = (uint4*)&sA[am * K2_LD + ai * 32];
      dst[0] = *(uint4*)&pk[0]; dst[1] = *(uint4*)&pk[4];
      dst[2] = *(uint4*)&pk[8]; dst[3] = *(uint4*)&pk[12];
    }
    __syncthreads();
    // issue next step's loads BEFORE MFMA so latency overlaps compute
    if (s + 1 < nst) {
      const int ibn = ib + 4;
      #pragma unroll
      for (int r = 0; r < 8; ++r)
        pb[r] = *((const uint4*)(w2f + (size_t)(o0 + brow + r * 16) * 16384 + (size_t)ibn * 32) + bcol);
      ph = H[(size_t)(n0 + am) * 512 + ibn + ai];
    }
    #pragma unroll
    for (int kk = 0; kk < 128; kk += 32) {
      half8 bfr[4], afr[2];
      #pragma unroll
      for (int fo = 0; fo < 4; ++fo)
        bfr[fo] = *(const half8*)&sB[(wo + fo * 16 + l16) * K2_LD + kk + quad * 8];
      #pragma unroll
      for (int fm = 0; fm < 2; ++fm)
        afr[fm] = *(const half8*)&sA[(wm + fm * 16 + l16) * K2_LD + kk + quad * 8];
      #pragma unroll
      for (int fm = 0; fm < 2; ++fm)
      #pragma unroll
      for (int fo = 0; fo < 4; ++fo)
        acc[fm][fo] = __builtin_amdgcn_mfma_f32_16x16x32_f16(afr[fm], bfr[fo], acc[fm][fo], 0, 0, 0);
    }
    __syncthreads();
  }
  float* Pk = P + (size_t)kz * (4096 * 512);
  #pragma unroll
  for (int fm = 0; fm < 2; ++fm)
  #pragma unroll
  for (int fo = 0; fo < 4; ++fo) {
    int o = o0 + wo + fo * 16 + l16;
    #pragma unroll
    for (int r = 0; r < 4; ++r) {
      int n = n0 + wm + fm * 16 + quad * 4 + r;
      Pk[(size_t)n * 512 + o] = acc[fm][fo][r];
    }
  }
}

// ---------------------------------------------------------------------------
// Reduce kan2 partials + bias2 -> H2 (kz runtime 2 or 3)
// ---------------------------------------------------------------------------
__global__ __launch_bounds__(256) void reduce2_kernel(
    const float* __restrict__ P, const void* __restrict__ bias2,
    const int* __restrict__ flag, float* __restrict__ H2, int kzT)
{
  int i = blockIdx.x * 256 + threadIdx.x;  // 524288 float4 groups
  const int isf = *flag;
  float4 a = ((const float4*)P)[i];
  float4 b = ((const float4*)(P + (size_t)4096 * 512))[i];
  float rx = a.x + b.x, ry = a.y + b.y, rz = a.z + b.z, rw = a.w + b.w;
  if (kzT == 3) {
    float4 c = ((const float4*)(P + (size_t)2 * 4096 * 512))[i];
    rx += c.x; ry += c.y; rz += c.z; rw += c.w;
  }
  int o = (i * 4) & 511;
  float4 r;
  r.x = rx + inval(bias2, o + 0, isf);
  r.y = ry + inval(bias2, o + 1, isf);
  r.z = rz + inval(bias2, o + 2, isf);
  r.w = rw + inval(bias2, o + 3, isf);
  ((float4*)H2)[i] = r;
}

// ---------------------------------------------------------------------------
// Kernel 4 v3: basis (grid=8) + fp16 GEMM, split-K kz=2, prefetch pipeline.
// Tile 32n x 128o. Grid (128,2,2). LDS 43520 B.
// ---------------------------------------------------------------------------
#define K3_LD 136
__global__ __launch_bounds__(256) void kan3_kernel(
    const float* __restrict__ H2, const u16* __restrict__ w3f,
    const int* __restrict__ flag, float* __restrict__ Q)
{
  __shared__ u16 sA[32 * K3_LD];
  __shared__ u16 sB[128 * K3_LD];
  const int n0 = blockIdx.x * 32, o0 = blockIdx.y * 128, kz = blockIdx.z;
  const int t = threadIdx.x, wave = t >> 6, lane = t & 63, quad = lane >> 4, l16 = lane & 15;
  const int wo = wave * 32;
  const int am = t >> 3, ai = t & 7;
  const int i0 = kz * 256;
  const int brow = t >> 4, bcol = t & 15;
  f32x4 acc[2][2] = {};
  uint4 pb[8]; float ph;
  #pragma unroll
  for (int r = 0; r < 8; ++r)
    pb[r] = *((const uint4*)(w3f + (size_t)(o0 + brow + r * 16) * 8192 + (size_t)i0 * 16) + bcol);
  ph = H2[(size_t)(n0 + am) * 512 + i0 + ai];
  for (int s = 0; s < 32; ++s) {
    const int ib = i0 + s * 8;
    float a = ph;
    float s1, c1; __sincosf(a, &s1, &c1);
    float cg[8], sg[8];
    cg[0] = c1; sg[0] = s1;
    #pragma unroll
    for (int g = 1; g < 8; ++g) {
      cg[g] = cg[g-1] * c1 - sg[g-1] * s1;
      sg[g] = sg[g-1] * c1 + cg[g-1] * s1;
    }
    u32 pk[8];
    #pragma unroll
    for (int j = 0; j < 4; ++j) pk[j] = packh2(cg[2*j], cg[2*j+1]);
    #pragma unroll
    for (int j = 0; j < 4; ++j) pk[4+j] = packh2(sg[2*j], sg[2*j+1]);
    #pragma unroll
    for (int r = 0; r < 8; ++r)
      *(uint4*)&sB[(brow + r * 16) * K3_LD + bcol * 8] = pb[r];
    {
      uint4* dst = (uint4*)&sA[am * K3_LD + ai * 16];
      dst[0] = *(uint4*)&pk[0]; dst[1] = *(uint4*)&pk[4];
    }
    __syncthreads();
    if (s + 1 < 32) {
      const int ibn = ib + 8;
      #pragma unroll
      for (int r = 0; r < 8; ++r)
        pb[r] = *((const uint4*)(w3f + (size_t)(o0 + brow + r * 16) * 8192 + (size_t)ibn * 16) + bcol);
      ph = H2[(size_t)(n0 + am) * 512 + ibn + ai];
    }
    #pragma unroll
    for (int kk = 0; kk < 128; kk += 32) {
      half8 bfr[2], afr[2];
      #pragma unroll
      for (int fo = 0; fo < 2; ++fo)
        bfr[fo] = *(const half8*)&sB[(wo + fo * 16 + l16) * K3_LD + kk + quad * 8];
      #pragma unroll
      for (int fm = 0; fm < 2; ++fm)
        afr[fm] = *(const half8*)&sA[(fm * 16 + l16) * K3_LD + kk + quad * 8];
      #pragma unroll
      for (int fm = 0; fm < 2; ++fm)
      #pragma unroll
      for (int fo = 0; fo < 2; ++fo)
        acc[fm][fo] = __builtin_amdgcn_mfma_f32_16x16x32_f16(afr[fm], bfr[fo], acc[fm][fo], 0, 0, 0);
    }
    __syncthreads();
  }
  float* Qk = Q + (size_t)kz * (4096 * 256);
  #pragma unroll
  for (int fm = 0; fm < 2; ++fm)
  #pragma unroll
  for (int fo = 0; fo < 2; ++fo) {
    int o = o0 + wo + fo * 16 + l16;
    #pragma unroll
    for (int r = 0; r < 4; ++r) {
      int n = n0 + fm * 16 + quad * 4 + r;
      Qk[(size_t)n * 256 + o] = acc[fm][fo][r];
    }
  }
}

// ---------------------------------------------------------------------------
// Kernel 5: fused partial-reduce + bias3 + row softmax + fp32 store.
// ---------------------------------------------------------------------------
__global__ __launch_bounds__(256) void softmax_kernel(
    const float* __restrict__ Q, const void* __restrict__ bias3,
    const int* __restrict__ flag, float* __restrict__ out)
{
  const int t = threadIdx.x, wave = t >> 6, lane = t & 63;
  const int row = blockIdx.x * 4 + wave;
  const int isf = *flag;
  size_t base = (size_t)row * 256 + lane * 4;
  float4 a = *(const float4*)(Q + base);
  float4 b = *(const float4*)(Q + (size_t)4096 * 256 + base);
  int o = lane * 4;
  float v0 = a.x + b.x + inval(bias3, o + 0, isf);
  float v1 = a.y + b.y + inval(bias3, o + 1, isf);
  float v2 = a.z + b.z + inval(bias3, o + 2, isf);
  float v3 = a.w + b.w + inval(bias3, o + 3, isf);
  float m = fmaxf(fmaxf(v0, v1), fmaxf(v2, v3));
  #pragma unroll
  for (int off = 32; off; off >>= 1) m = fmaxf(m, __shfl_xor(m, off));
  float e0 = __expf(v0 - m), e1 = __expf(v1 - m), e2 = __expf(v2 - m), e3 = __expf(v3 - m);
  float s = e0 + e1 + e2 + e3;
  #pragma unroll
  for (int off = 32; off; off >>= 1) s += __shfl_xor(s, off);
  float inv = 1.f / s;
  *(float4*)(out + base) = make_float4(e0 * inv, e1 * inv, e2 * inv, e3 * inv);
}

// ---------------------------------------------------------------------------
extern "C" void kernel_launch(void* const* d_in, const int* in_sizes, int n_in,
                              void* d_out, int out_size, void* d_ws, size_t ws_size,
                              hipStream_t stream)
{
  const void* x     = d_in[0];
  const void* W1    = d_in[1];
  const void* b1    = d_in[2];
  const void* gamma = d_in[3];
  const void* beta  = d_in[4];
  const void* c2    = d_in[5];
  const void* bias2 = d_in[6];
  const void* c3    = d_in[7];
  const void* bias3 = d_in[8];

  // kz for kan2: 3 if workspace permits the 24 MB partials, else 2.
  // (ws_size is constant across calls -> same work every call.)
  const int kz2 = (ws_size >= (61ull << 20) + 262144) ? 3 : 2;

  char* ws = (char*)d_ws;
  float*  H    = (float*)(ws + 0);                        // 8 MB [l1 -> kan2]
  float*  H2   = (float*)(ws + (8ull  << 20));            // 8 MB [reduce2 -> kan3]
  u16*    W2F  = (u16*)  (ws + (16ull << 20));            // 16 MB [prep2 -> kan2]
  u16*    W3F  = (u16*)  (ws + (32ull << 20));            // 4 MB  [prep3 -> kan3]
  u16*    Xs   = (u16*)  (ws + (36ull << 20));            // 6.3 MB [split -> l1], dead after
  u16*    W1s  = (u16*)  (ws + (43ull << 20));            // 0.79 MB [split -> l1], dead after
  float*  P2   = (float*)(ws + (36ull << 20));            // kz2*8 MB [kan2 -> reduce2]
  float*  Q3   = (float*)(ws + 0);                        // 8 MB [kan3 -> softmax], aliases H
  size_t  tail = (kz2 == 3) ? (61ull << 20) : (52ull << 20);
  float2* PT   = (float2*)(ws + tail);                    // 2 KB
  float*  STT  = (float*) (ws + tail + 65536);            // 8 B
  int*    FLAG = (int*)   (ws + tail + 131072);           // 4 B

  detect_kernel<<<dim3(1), dim3(64), 0, stream>>>((const u16*)W1, FLAG);
  split_kernel<<<dim3(1024), dim3(256), 0, stream>>>(x,  Xs,  FLAG, 262144, 1);
  split_kernel<<<dim3(128),  dim3(256), 0, stream>>>(W1, W1s, FLAG, 32768,  2);
  prep2_kernel<<<dim3(1024), dim3(256), 0, stream>>>(c2, W2F, FLAG);
  prep3_kernel<<<dim3(512),  dim3(256), 0, stream>>>(c3, W3F, FLAG);
  l1_kernel   <<<dim3(32, 8), dim3(256), 0, stream>>>(Xs, W1s, b1, FLAG, H, PT);
  red_kernel  <<<dim3(1),    dim3(256), 0, stream>>>(PT, STT);
  kan2_kernel <<<dim3(64, 4, kz2), dim3(256), 0, stream>>>(H, W2F, gamma, beta, FLAG, STT, P2, kz2);
  reduce2_kernel<<<dim3(2048), dim3(256), 0, stream>>>(P2, bias2, FLAG, H2, kz2);
  kan3_kernel <<<dim3(128, 2, 2), dim3(256), 0, stream>>>(H2, W3F, FLAG, Q3);
  softmax_kernel<<<dim3(1024), dim3(256), 0, stream>>>(Q3, bias3, FLAG, (float*)d_out);
}

// Round 8
// 294.825 us; speedup vs baseline: 1.9494x; 1.9494x over previous
//
#include <hip/hip_runtime.h>
#include <hip/hip_fp16.h>
#include <stdint.h>

typedef unsigned short u16;
typedef unsigned int u32;
typedef short bf16x8 __attribute__((ext_vector_type(8)));
typedef _Float16 half8 __attribute__((ext_vector_type(8)));
typedef __fp16 fp16x2 __attribute__((ext_vector_type(2)));
typedef float f32x4 __attribute__((ext_vector_type(4)));

__device__ __forceinline__ float bf2f(u16 v) { return __uint_as_float(((u32)v) << 16); }

__device__ __forceinline__ u16 f2bf(float a) {
  u32 u = __float_as_uint(a); u += 0x7FFFu + ((u >> 16) & 1u); return (u16)(u >> 16);
}

__device__ __forceinline__ u32 packbf2(float a, float b) {
  u32 ua = __float_as_uint(a); ua += 0x7FFFu + ((ua >> 16) & 1u);
  u32 ub = __float_as_uint(b); ub += 0x7FFFu + ((ub >> 16) & 1u);
  return (ua >> 16) | (ub & 0xFFFF0000u);
}

// one v_cvt_pkrtz_f16_f32: two f32 -> packed 2xf16 (RTZ; margin 3.7x, fine)
__device__ __forceinline__ u32 packh2(float a, float b) {
  union { fp16x2 h; u32 u; } cv;
  cv.h = __builtin_amdgcn_cvt_pkrtz(a, b);
  return cv.u;
}

__device__ __forceinline__ float inval(const void* p, int idx, int isf) {
  return isf ? ((const float*)p)[idx] : bf2f(((const u16*)p)[idx]);
}

// ---------------------------------------------------------------------------
// Detect input dtype: flag=1 -> fp32 inputs (verified r3/r4 on this dataset).
// ---------------------------------------------------------------------------
__global__ void detect_kernel(const u16* __restrict__ w1raw, int* __restrict__ flag)
{
  int lane = threadIdx.x & 63;
  float m = 0.f;
  #pragma unroll
  for (int j = 0; j < 2; ++j) {
    float v = fabsf(bf2f(w1raw[lane + j * 64]));
    if (!(v < 1e6f)) v = 1e30f;
    m = fmaxf(m, v);
  }
  #pragma unroll
  for (int off = 32; off; off >>= 1) m = fmaxf(m, __shfl_xor(m, off));
  if (lane == 0) *flag = (m > 1e6f) ? 1 : 0;
}

// ---------------------------------------------------------------------------
// Split ingest: row 256 -> 768 bf16 cols. lo_pos=1: [hi|lo|hi]; 2: [hi|hi|lo].
// ---------------------------------------------------------------------------
__global__ __launch_bounds__(256) void split_kernel(
    const void* __restrict__ src, u16* __restrict__ dst,
    const int* __restrict__ flag, int n4, int lo_pos)
{
  int i = blockIdx.x * 256 + threadIdx.x;
  if (i >= n4) return;
  int row = i >> 6, g = i & 63;
  float v[4];
  if (*flag) {
    float4 t = ((const float4*)src)[i];
    v[0] = t.x; v[1] = t.y; v[2] = t.z; v[3] = t.w;
  } else {
    uint2 t = ((const uint2*)src)[i];
    const u16* p = (const u16*)&t;
    v[0] = bf2f(p[0]); v[1] = bf2f(p[1]); v[2] = bf2f(p[2]); v[3] = bf2f(p[3]);
  }
  u16 hi[4]; float lo[4];
  #pragma unroll
  for (int j = 0; j < 4; ++j) { hi[j] = f2bf(v[j]); lo[j] = v[j] - bf2f(hi[j]); }
  u32 hw0 = (u32)hi[0] | ((u32)hi[1] << 16);
  u32 hw1 = (u32)hi[2] | ((u32)hi[3] << 16);
  u32 lw0 = packbf2(lo[0], lo[1]);
  u32 lw1 = packbf2(lo[2], lo[3]);
  u32* base = (u32*)(dst + (size_t)row * 768);
  int c = g * 2;
  base[c] = hw0; base[c + 1] = hw1;
  if (lo_pos == 1) {
    base[128 + c] = lw0; base[128 + c + 1] = lw1;
    base[256 + c] = hw0; base[256 + c + 1] = hw1;
  } else {
    base[128 + c] = hw0; base[128 + c + 1] = hw1;
    base[256 + c] = lw0; base[256 + c + 1] = lw1;
  }
}

// ---------------------------------------------------------------------------
// Kernel 1: h = x @ W1^T + b1 via split-bf16 (K=768), fp32 out + sum/sumsq.
// Tile 128n x 64o, grid (32,8).
// ---------------------------------------------------------------------------
#define L1_LD 136
__global__ __launch_bounds__(256) void l1_kernel(
    const u16* __restrict__ xs, const u16* __restrict__ w1s, const void* __restrict__ b1,
    const int* __restrict__ flag, float* __restrict__ H, float2* __restrict__ PT)
{
  __shared__ u16 sA[128 * L1_LD];
  __shared__ u16 sB[64 * L1_LD];
  __shared__ float redbuf[8];
  const int n0 = blockIdx.x * 128, o0 = blockIdx.y * 64;
  const int t = threadIdx.x, wave = t >> 6, lane = t & 63, quad = lane >> 4, l16 = lane & 15;
  const int isf = *flag;
  f32x4 acc[2][4] = {};
  for (int ks = 0; ks < 768; ks += 128) {
    #pragma unroll
    for (int r = 0; r < 8; ++r) {
      int idx = t + r * 256;
      int row = idx >> 4, col = idx & 15;
      const uint4* src = (const uint4*)(xs + (size_t)(n0 + row) * 768 + ks) + col;
      *(uint4*)&sA[row * L1_LD + col * 8] = *src;
    }
    #pragma unroll
    for (int r = 0; r < 4; ++r) {
      int idx = t + r * 256;
      int row = idx >> 4, col = idx & 15;
      const uint4* src = (const uint4*)(w1s + (size_t)(o0 + row) * 768 + ks) + col;
      *(uint4*)&sB[row * L1_LD + col * 8] = *src;
    }
    __syncthreads();
    #pragma unroll
    for (int kk = 0; kk < 128; kk += 32) {
      bf16x8 bfr[4];
      #pragma unroll
      for (int fo = 0; fo < 4; ++fo)
        bfr[fo] = *(const bf16x8*)&sB[(fo * 16 + l16) * L1_LD + kk + quad * 8];
      #pragma unroll
      for (int fm = 0; fm < 2; ++fm) {
        bf16x8 av = *(const bf16x8*)&sA[(wave * 32 + fm * 16 + l16) * L1_LD + kk + quad * 8];
        #pragma unroll
        for (int fo = 0; fo < 4; ++fo)
          acc[fm][fo] = __builtin_amdgcn_mfma_f32_16x16x32_bf16(av, bfr[fo], acc[fm][fo], 0, 0, 0);
      }
    }
    __syncthreads();
  }
  float s = 0.f, sq = 0.f;
  #pragma unroll
  for (int fm = 0; fm < 2; ++fm)
  #pragma unroll
  for (int fo = 0; fo < 4; ++fo) {
    int o = o0 + fo * 16 + l16;
    float bias = inval(b1, o, isf);
    #pragma unroll
    for (int r = 0; r < 4; ++r) {
      int n = n0 + wave * 32 + fm * 16 + quad * 4 + r;
      float h = acc[fm][fo][r] + bias;
      H[(size_t)n * 512 + o] = h;
      s += h; sq += h * h;
    }
  }
  #pragma unroll
  for (int off = 32; off; off >>= 1) { s += __shfl_down(s, off); sq += __shfl_down(sq, off); }
  if (lane == 0) { redbuf[wave] = s; redbuf[4 + wave] = sq; }
  __syncthreads();
  if (t == 0) {
    float S = redbuf[0] + redbuf[1] + redbuf[2] + redbuf[3];
    float Q = redbuf[4] + redbuf[5] + redbuf[6] + redbuf[7];
    PT[blockIdx.y * 32 + blockIdx.x] = make_float2(S, Q);
  }
}

// ---------------------------------------------------------------------------
// Kernel 2: reduce 256 partials -> mean, rsqrt(var+eps)
// ---------------------------------------------------------------------------
__global__ __launch_bounds__(256) void red_kernel(const float2* __restrict__ PT, float* __restrict__ ST)
{
  __shared__ float sa[4], sb[4];
  const int t = threadIdx.x;
  float2 p = PT[t];
  float s = p.x, q = p.y;
  #pragma unroll
  for (int off = 32; off; off >>= 1) { s += __shfl_down(s, off); q += __shfl_down(q, off); }
  if ((t & 63) == 0) { sa[t >> 6] = s; sb[t >> 6] = q; }
  __syncthreads();
  if (t == 0) {
    float S = sa[0] + sa[1] + sa[2] + sa[3];
    float Q = sb[0] + sb[1] + sb[2] + sb[3];
    const float N = 4096.f * 512.f;
    float mean = S / N;
    float var = Q / N - mean * mean;
    ST[0] = mean;
    ST[1] = rsqrtf(var + 1e-5f);
  }
}

// ---------------------------------------------------------------------------
// Prep: reorder coeffs to K-interleaved fp16 rows.
// ---------------------------------------------------------------------------
__global__ __launch_bounds__(256) void prep2_kernel(
    const void* __restrict__ c2, u16* __restrict__ w2f, const int* __restrict__ flag)
{
  int u = blockIdx.x * 256 + threadIdx.x;  // 512*512
  int o = u >> 9, i = u & 511;
  u32* d = (u32*)(w2f + (size_t)o * 16384 + i * 32);
  if (*flag) {
    const float4* f0 = (const float4*)((const float*)c2 + ((size_t)o * 512 + i) * 16);
    const float4* f1 = (const float4*)((const float*)c2 + (size_t)512 * 512 * 16 + ((size_t)o * 512 + i) * 16);
    #pragma unroll
    for (int j = 0; j < 4; ++j) { float4 v = f0[j]; d[2*j] = packh2(v.x, v.y); d[2*j+1] = packh2(v.z, v.w); }
    #pragma unroll
    for (int j = 0; j < 4; ++j) { float4 v = f1[j]; d[8+2*j] = packh2(v.x, v.y); d[8+2*j+1] = packh2(v.z, v.w); }
  } else {
    const u16* s0 = (const u16*)c2 + ((size_t)o * 512 + i) * 16;
    const u16* s1 = (const u16*)c2 + (size_t)512 * 512 * 16 + ((size_t)o * 512 + i) * 16;
    #pragma unroll
    for (int j = 0; j < 8; ++j) d[j]   = packh2(bf2f(s0[2*j]), bf2f(s0[2*j+1]));
    #pragma unroll
    for (int j = 0; j < 8; ++j) d[8+j] = packh2(bf2f(s1[2*j]), bf2f(s1[2*j+1]));
  }
}

__global__ __launch_bounds__(256) void prep3_kernel(
    const void* __restrict__ c3, u16* __restrict__ w3f, const int* __restrict__ flag)
{
  int u = blockIdx.x * 256 + threadIdx.x;  // 256*512
  int o = u >> 9, i = u & 511;
  u32* d = (u32*)(w3f + (size_t)o * 8192 + i * 16);
  if (*flag) {
    const float4* f0 = (const float4*)((const float*)c3 + ((size_t)o * 512 + i) * 8);
    const float4* f1 = (const float4*)((const float*)c3 + (size_t)256 * 512 * 8 + ((size_t)o * 512 + i) * 8);
    #pragma unroll
    for (int j = 0; j < 2; ++j) { float4 v = f0[j]; d[2*j] = packh2(v.x, v.y); d[2*j+1] = packh2(v.z, v.w); }
    #pragma unroll
    for (int j = 0; j < 2; ++j) { float4 v = f1[j]; d[4+2*j] = packh2(v.x, v.y); d[4+2*j+1] = packh2(v.z, v.w); }
  } else {
    const u16* s0 = (const u16*)c3 + ((size_t)o * 512 + i) * 8;
    const u16* s1 = (const u16*)c3 + (size_t)256 * 512 * 8 + ((size_t)o * 512 + i) * 8;
    #pragma unroll
    for (int j = 0; j < 4; ++j) d[j]   = packh2(bf2f(s0[2*j]), bf2f(s0[2*j+1]));
    #pragma unroll
    for (int j = 0; j < 4; ++j) d[4+j] = packh2(bf2f(s1[2*j]), bf2f(s1[2*j+1]));
  }
}

// ---------------------------------------------------------------------------
// Kernel 3 (r5 body, no register prefetch): fused BN+ReLU+basis + fp16 GEMM,
// split-K (kz=2 or 3). Tile 64n x 128o. LDS 52224 B -> 3 blocks/CU.
// ---------------------------------------------------------------------------
#define K2_LD 136
__global__ __launch_bounds__(256) void kan2_kernel(
    const float* __restrict__ H, const u16* __restrict__ w2f,
    const void* __restrict__ gammap, const void* __restrict__ betap,
    const int* __restrict__ flag, const float* __restrict__ ST,
    float* __restrict__ P, int kzT)
{
  __shared__ u16 sA[64 * K2_LD];
  __shared__ u16 sB[128 * K2_LD];
  const int n0 = blockIdx.x * 64, o0 = blockIdx.y * 128, kz = blockIdx.z;
  const int t = threadIdx.x, wave = t >> 6, lane = t & 63, quad = lane >> 4, l16 = lane & 15;
  const int wm = (wave & 1) * 32, wo = (wave >> 1) * 64;
  const int isf = *flag;
  const float mean = ST[0];
  const float gs = inval(gammap, 0, isf) * ST[1];
  const float beta = inval(betap, 0, isf);
  const int am = t >> 2, ai = t & 3;
  int i0, nst;
  if (kzT == 3) { i0 = (kz == 0) ? 0 : (kz == 1) ? 172 : 344; nst = (kz < 2) ? 43 : 42; }
  else          { i0 = kz * 256; nst = 64; }
  const int brow = t >> 4, bcol = t & 15;
  const u16* bsrc = w2f + (size_t)(o0 + brow) * 16384 + (size_t)i0 * 32 + bcol * 8;
  const float* hsrc = H + (size_t)(n0 + am) * 512 + i0 + ai;
  f32x4 acc[2][4] = {};
  for (int s = 0; s < nst; ++s) {
    // B stage: load->LDS immediately (transient regs only; r6's held prefetch spilled)
    #pragma unroll
    for (int r = 0; r < 8; ++r) {
      uint4 v = *(const uint4*)(bsrc + (size_t)r * 16 * 16384);
      *(uint4*)&sB[(brow + r * 16) * K2_LD + bcol * 8] = v;
    }
    // A stage: 1 (m,i) pair per thread
    {
      float h = *hsrc;
      float a = fmaxf((h - mean) * gs + beta, 0.f);
      float s1, c1; __sincosf(a, &s1, &c1);
      float cg[16], sg[16];
      cg[0] = c1; sg[0] = s1;
      #pragma unroll
      for (int g = 1; g < 16; ++g) {
        cg[g] = cg[g-1] * c1 - sg[g-1] * s1;
        sg[g] = sg[g-1] * c1 + cg[g-1] * s1;
      }
      u32 pk[16];
      #pragma unroll
      for (int j = 0; j < 8; ++j) pk[j] = packh2(cg[2*j], cg[2*j+1]);
      #pragma unroll
      for (int j = 0; j < 8; ++j) pk[8+j] = packh2(sg[2*j], sg[2*j+1]);
      uint4* dst = (uint4*)&sA[am * K2_LD + ai * 32];
      dst[0] = *(uint4*)&pk[0]; dst[1] = *(uint4*)&pk[4];
      dst[2] = *(uint4*)&pk[8]; dst[3] = *(uint4*)&pk[12];
    }
    __syncthreads();
    bsrc += 128; hsrc += 4;
    #pragma unroll
    for (int kk = 0; kk < 128; kk += 32) {
      half8 bfr[4], afr[2];
      #pragma unroll
      for (int fo = 0; fo < 4; ++fo)
        bfr[fo] = *(const half8*)&sB[(wo + fo * 16 + l16) * K2_LD + kk + quad * 8];
      #pragma unroll
      for (int fm = 0; fm < 2; ++fm)
        afr[fm] = *(const half8*)&sA[(wm + fm * 16 + l16) * K2_LD + kk + quad * 8];
      #pragma unroll
      for (int fm = 0; fm < 2; ++fm)
      #pragma unroll
      for (int fo = 0; fo < 4; ++fo)
        acc[fm][fo] = __builtin_amdgcn_mfma_f32_16x16x32_f16(afr[fm], bfr[fo], acc[fm][fo], 0, 0, 0);
    }
    __syncthreads();
  }
  float* Pk = P + (size_t)kz * (4096 * 512);
  #pragma unroll
  for (int fm = 0; fm < 2; ++fm)
  #pragma unroll
  for (int fo = 0; fo < 4; ++fo) {
    int o = o0 + wo + fo * 16 + l16;
    #pragma unroll
    for (int r = 0; r < 4; ++r) {
      int n = n0 + wm + fm * 16 + quad * 4 + r;
      Pk[(size_t)n * 512 + o] = acc[fm][fo][r];
    }
  }
}

// ---------------------------------------------------------------------------
// Reduce kan2 partials + bias2 -> H2 (kz runtime 2 or 3)
// ---------------------------------------------------------------------------
__global__ __launch_bounds__(256) void reduce2_kernel(
    const float* __restrict__ P, const void* __restrict__ bias2,
    const int* __restrict__ flag, float* __restrict__ H2, int kzT)
{
  int i = blockIdx.x * 256 + threadIdx.x;  // 524288 float4 groups
  const int isf = *flag;
  float4 a = ((const float4*)P)[i];
  float4 b = ((const float4*)(P + (size_t)4096 * 512))[i];
  float rx = a.x + b.x, ry = a.y + b.y, rz = a.z + b.z, rw = a.w + b.w;
  if (kzT == 3) {
    float4 c = ((const float4*)(P + (size_t)2 * 4096 * 512))[i];
    rx += c.x; ry += c.y; rz += c.z; rw += c.w;
  }
  int o = (i * 4) & 511;
  float4 r;
  r.x = rx + inval(bias2, o + 0, isf);
  r.y = ry + inval(bias2, o + 1, isf);
  r.z = rz + inval(bias2, o + 2, isf);
  r.w = rw + inval(bias2, o + 3, isf);
  ((float4*)H2)[i] = r;
}

// ---------------------------------------------------------------------------
// Kernel 4 (r5 body): basis (grid=8) + fp16 GEMM, split-K kz=2.
// Tile 32n x 128o. Grid (128,2,2). LDS 43520 B.
// ---------------------------------------------------------------------------
#define K3_LD 136
__global__ __launch_bounds__(256) void kan3_kernel(
    const float* __restrict__ H2, const u16* __restrict__ w3f,
    const int* __restrict__ flag, float* __restrict__ Q)
{
  __shared__ u16 sA[32 * K3_LD];
  __shared__ u16 sB[128 * K3_LD];
  const int n0 = blockIdx.x * 32, o0 = blockIdx.y * 128, kz = blockIdx.z;
  const int t = threadIdx.x, wave = t >> 6, lane = t & 63, quad = lane >> 4, l16 = lane & 15;
  const int wo = wave * 32;
  const int am = t >> 3, ai = t & 7;
  const int i0 = kz * 256;
  const int brow = t >> 4, bcol = t & 15;
  const u16* bsrc = w3f + (size_t)(o0 + brow) * 8192 + (size_t)i0 * 16 + bcol * 8;
  const float* hsrc = H2 + (size_t)(n0 + am) * 512 + i0 + ai;
  f32x4 acc[2][2] = {};
  for (int s = 0; s < 32; ++s) {
    #pragma unroll
    for (int r = 0; r < 8; ++r) {
      uint4 v = *(const uint4*)(bsrc + (size_t)r * 16 * 8192);
      *(uint4*)&sB[(brow + r * 16) * K3_LD + bcol * 8] = v;
    }
    {
      float a = *hsrc;
      float s1, c1; __sincosf(a, &s1, &c1);
      float cg[8], sg[8];
      cg[0] = c1; sg[0] = s1;
      #pragma unroll
      for (int g = 1; g < 8; ++g) {
        cg[g] = cg[g-1] * c1 - sg[g-1] * s1;
        sg[g] = sg[g-1] * c1 + cg[g-1] * s1;
      }
      u32 pk[8];
      #pragma unroll
      for (int j = 0; j < 4; ++j) pk[j] = packh2(cg[2*j], cg[2*j+1]);
      #pragma unroll
      for (int j = 0; j < 4; ++j) pk[4+j] = packh2(sg[2*j], sg[2*j+1]);
      uint4* dst = (uint4*)&sA[am * K3_LD + ai * 16];
      dst[0] = *(uint4*)&pk[0]; dst[1] = *(uint4*)&pk[4];
    }
    __syncthreads();
    bsrc += 128; hsrc += 8;
    #pragma unroll
    for (int kk = 0; kk < 128; kk += 32) {
      half8 bfr[2], afr[2];
      #pragma unroll
      for (int fo = 0; fo < 2; ++fo)
        bfr[fo] = *(const half8*)&sB[(wo + fo * 16 + l16) * K3_LD + kk + quad * 8];
      #pragma unroll
      for (int fm = 0; fm < 2; ++fm)
        afr[fm] = *(const half8*)&sA[(fm * 16 + l16) * K3_LD + kk + quad * 8];
      #pragma unroll
      for (int fm = 0; fm < 2; ++fm)
      #pragma unroll
      for (int fo = 0; fo < 2; ++fo)
        acc[fm][fo] = __builtin_amdgcn_mfma_f32_16x16x32_f16(afr[fm], bfr[fo], acc[fm][fo], 0, 0, 0);
    }
    __syncthreads();
  }
  float* Qk = Q + (size_t)kz * (4096 * 256);
  #pragma unroll
  for (int fm = 0; fm < 2; ++fm)
  #pragma unroll
  for (int fo = 0; fo < 2; ++fo) {
    int o = o0 + wo + fo * 16 + l16;
    #pragma unroll
    for (int r = 0; r < 4; ++r) {
      int n = n0 + fm * 16 + quad * 4 + r;
      Qk[(size_t)n * 256 + o] = acc[fm][fo][r];
    }
  }
}

// ---------------------------------------------------------------------------
// Kernel 5: fused partial-reduce + bias3 + row softmax + fp32 store.
// ---------------------------------------------------------------------------
__global__ __launch_bounds__(256) void softmax_kernel(
    const float* __restrict__ Q, const void* __restrict__ bias3,
    const int* __restrict__ flag, float* __restrict__ out)
{
  const int t = threadIdx.x, wave = t >> 6, lane = t & 63;
  const int row = blockIdx.x * 4 + wave;
  const int isf = *flag;
  size_t base = (size_t)row * 256 + lane * 4;
  float4 a = *(const float4*)(Q + base);
  float4 b = *(const float4*)(Q + (size_t)4096 * 256 + base);
  int o = lane * 4;
  float v0 = a.x + b.x + inval(bias3, o + 0, isf);
  float v1 = a.y + b.y + inval(bias3, o + 1, isf);
  float v2 = a.z + b.z + inval(bias3, o + 2, isf);
  float v3 = a.w + b.w + inval(bias3, o + 3, isf);
  float m = fmaxf(fmaxf(v0, v1), fmaxf(v2, v3));
  #pragma unroll
  for (int off = 32; off; off >>= 1) m = fmaxf(m, __shfl_xor(m, off));
  float e0 = __expf(v0 - m), e1 = __expf(v1 - m), e2 = __expf(v2 - m), e3 = __expf(v3 - m);
  float s = e0 + e1 + e2 + e3;
  #pragma unroll
  for (int off = 32; off; off >>= 1) s += __shfl_xor(s, off);
  float inv = 1.f / s;
  *(float4*)(out + base) = make_float4(e0 * inv, e1 * inv, e2 * inv, e3 * inv);
}

// ---------------------------------------------------------------------------
extern "C" void kernel_launch(void* const* d_in, const int* in_sizes, int n_in,
                              void* d_out, int out_size, void* d_ws, size_t ws_size,
                              hipStream_t stream)
{
  const void* x     = d_in[0];
  const void* W1    = d_in[1];
  const void* b1    = d_in[2];
  const void* gamma = d_in[3];
  const void* beta  = d_in[4];
  const void* c2    = d_in[5];
  const void* bias2 = d_in[6];
  const void* c3    = d_in[7];
  const void* bias3 = d_in[8];

  // kz for kan2: 3 if workspace permits the 24 MB partials, else 2.
  const int kz2 = (ws_size >= (61ull << 20) + 262144) ? 3 : 2;

  char* ws = (char*)d_ws;
  float*  H    = (float*)(ws + 0);                        // 8 MB [l1 -> kan2]
  float*  H2   = (float*)(ws + (8ull  << 20));            // 8 MB [reduce2 -> kan3]
  u16*    W2F  = (u16*)  (ws + (16ull << 20));            // 16 MB [prep2 -> kan2]
  u16*    W3F  = (u16*)  (ws + (32ull << 20));            // 4 MB  [prep3 -> kan3]
  u16*    Xs   = (u16*)  (ws + (36ull << 20));            // 6.3 MB [split -> l1], dead after
  u16*    W1s  = (u16*)  (ws + (43ull << 20));            // 0.79 MB [split -> l1], dead after
  float*  P2   = (float*)(ws + (36ull << 20));            // kz2*8 MB [kan2 -> reduce2]
  float*  Q3   = (float*)(ws + 0);                        // 8 MB [kan3 -> softmax], aliases H
  size_t  tail = (kz2 == 3) ? (61ull << 20) : (52ull << 20);
  float2* PT   = (float2*)(ws + tail);                    // 2 KB
  float*  STT  = (float*) (ws + tail + 65536);            // 8 B
  int*    FLAG = (int*)   (ws + tail + 131072);           // 4 B

  detect_kernel<<<dim3(1), dim3(64), 0, stream>>>((const u16*)W1, FLAG);
  split_kernel<<<dim3(1024), dim3(256), 0, stream>>>(x,  Xs,  FLAG, 262144, 1);
  split_kernel<<<dim3(128),  dim3(256), 0, stream>>>(W1, W1s, FLAG, 32768,  2);
  prep2_kernel<<<dim3(1024), dim3(256), 0, stream>>>(c2, W2F, FLAG);
  prep3_kernel<<<dim3(512),  dim3(256), 0, stream>>>(c3, W3F, FLAG);
  l1_kernel   <<<dim3(32, 8), dim3(256), 0, stream>>>(Xs, W1s, b1, FLAG, H, PT);
  red_kernel  <<<dim3(1),    dim3(256), 0, stream>>>(PT, STT);
  kan2_kernel <<<dim3(64, 4, kz2), dim3(256), 0, stream>>>(H, W2F, gamma, beta, FLAG, STT, P2, kz2);
  reduce2_kernel<<<dim3(2048), dim3(256), 0, stream>>>(P2, bias2, FLAG, H2, kz2);
  kan3_kernel <<<dim3(128, 2, 2), dim3(256), 0, stream>>>(H2, W3F, FLAG, Q3);
  softmax_kernel<<<dim3(1024), dim3(256), 0, stream>>>(Q3, bias3, FLAG, (float*)d_out);
}

// Round 9
// 265.871 us; speedup vs baseline: 2.1617x; 1.1089x over previous
//
#include <hip/hip_runtime.h>
#include <hip/hip_fp16.h>
#include <stdint.h>

typedef unsigned short u16;
typedef unsigned int u32;
typedef short bf16x8 __attribute__((ext_vector_type(8)));
typedef _Float16 half8 __attribute__((ext_vector_type(8)));
typedef __fp16 fp16x2 __attribute__((ext_vector_type(2)));
typedef float f32x4 __attribute__((ext_vector_type(4)));

__device__ __forceinline__ float bf2f(u16 v) { return __uint_as_float(((u32)v) << 16); }

__device__ __forceinline__ u16 f2bf(float a) {
  u32 u = __float_as_uint(a); u += 0x7FFFu + ((u >> 16) & 1u); return (u16)(u >> 16);
}

__device__ __forceinline__ u32 packbf2(float a, float b) {
  u32 ua = __float_as_uint(a); ua += 0x7FFFu + ((ua >> 16) & 1u);
  u32 ub = __float_as_uint(b); ub += 0x7FFFu + ((ub >> 16) & 1u);
  return (ua >> 16) | (ub & 0xFFFF0000u);
}

// one v_cvt_pkrtz_f16_f32: two f32 -> packed 2xf16 (RTZ; margin 3.7x, fine)
__device__ __forceinline__ u32 packh2(float a, float b) {
  union { fp16x2 h; u32 u; } cv;
  cv.h = __builtin_amdgcn_cvt_pkrtz(a, b);
  return cv.u;
}

__device__ __forceinline__ float inval(const void* p, int idx, int isf) {
  return isf ? ((const float*)p)[idx] : bf2f(((const u16*)p)[idx]);
}

// ---------------------------------------------------------------------------
// prep_all: one launch replacing detect + split(x) + split(W1) + prep2 + prep3.
// Each block locally detects input dtype from W1's first 128 u16 (fp32 read as
// bf16 -> mantissa halves -> huge/NaN with certainty). Block 0 publishes FLAG
// for downstream kernels.
// Grid 2688: [0,1024) split x | [1024,1152) split W1 | [1152,2176) prep2 |
// [2176,2688) prep3.
// ---------------------------------------------------------------------------
__device__ __forceinline__ void split_body(
    const void* __restrict__ src, u16* __restrict__ dst, int i, int isf, int lo_pos)
{
  int row = i >> 6, g = i & 63;
  float v[4];
  if (isf) {
    float4 t = ((const float4*)src)[i];
    v[0] = t.x; v[1] = t.y; v[2] = t.z; v[3] = t.w;
  } else {
    uint2 t = ((const uint2*)src)[i];
    const u16* p = (const u16*)&t;
    v[0] = bf2f(p[0]); v[1] = bf2f(p[1]); v[2] = bf2f(p[2]); v[3] = bf2f(p[3]);
  }
  u16 hi[4]; float lo[4];
  #pragma unroll
  for (int j = 0; j < 4; ++j) { hi[j] = f2bf(v[j]); lo[j] = v[j] - bf2f(hi[j]); }
  u32 hw0 = (u32)hi[0] | ((u32)hi[1] << 16);
  u32 hw1 = (u32)hi[2] | ((u32)hi[3] << 16);
  u32 lw0 = packbf2(lo[0], lo[1]);
  u32 lw1 = packbf2(lo[2], lo[3]);
  u32* base = (u32*)(dst + (size_t)row * 768);
  int c = g * 2;
  base[c] = hw0; base[c + 1] = hw1;
  if (lo_pos == 1) {
    base[128 + c] = lw0; base[128 + c + 1] = lw1;
    base[256 + c] = hw0; base[256 + c + 1] = hw1;
  } else {
    base[128 + c] = hw0; base[128 + c + 1] = hw1;
    base[256 + c] = lw0; base[256 + c + 1] = lw1;
  }
}

__global__ __launch_bounds__(256) void prep_all_kernel(
    const void* __restrict__ x, const void* __restrict__ W1,
    u16* __restrict__ Xs, u16* __restrict__ W1s,
    const void* __restrict__ c2, u16* __restrict__ w2f,
    const void* __restrict__ c3, u16* __restrict__ w3f,
    int* __restrict__ flag)
{
  __shared__ int sf[4];
  const int t = threadIdx.x, wave = t >> 6;
  {
    float v = fabsf(bf2f(((const u16*)W1)[t & 127]));
    int bad = !(v < 1e6f);
    unsigned long long b = __ballot(bad);
    if ((t & 63) == 0) sf[wave] = (b != 0ull) ? 1 : 0;
  }
  __syncthreads();
  const int isf = sf[0] | sf[1] | sf[2] | sf[3];
  const int bid = blockIdx.x;
  if (bid == 0 && t == 0) *flag = isf;
  if (bid < 1024) {
    split_body(x, Xs, bid * 256 + t, isf, 1);
  } else if (bid < 1152) {
    split_body(W1, W1s, (bid - 1024) * 256 + t, isf, 2);
  } else if (bid < 2176) {
    int u = (bid - 1152) * 256 + t;           // 512*512
    int o = u >> 9, i = u & 511;
    u32* d = (u32*)(w2f + (size_t)o * 16384 + i * 32);
    if (isf) {
      const float4* f0 = (const float4*)((const float*)c2 + ((size_t)o * 512 + i) * 16);
      const float4* f1 = (const float4*)((const float*)c2 + (size_t)512 * 512 * 16 + ((size_t)o * 512 + i) * 16);
      #pragma unroll
      for (int j = 0; j < 4; ++j) { float4 v = f0[j]; d[2*j] = packh2(v.x, v.y); d[2*j+1] = packh2(v.z, v.w); }
      #pragma unroll
      for (int j = 0; j < 4; ++j) { float4 v = f1[j]; d[8+2*j] = packh2(v.x, v.y); d[8+2*j+1] = packh2(v.z, v.w); }
    } else {
      const u16* s0 = (const u16*)c2 + ((size_t)o * 512 + i) * 16;
      const u16* s1 = (const u16*)c2 + (size_t)512 * 512 * 16 + ((size_t)o * 512 + i) * 16;
      #pragma unroll
      for (int j = 0; j < 8; ++j) d[j]   = packh2(bf2f(s0[2*j]), bf2f(s0[2*j+1]));
      #pragma unroll
      for (int j = 0; j < 8; ++j) d[8+j] = packh2(bf2f(s1[2*j]), bf2f(s1[2*j+1]));
    }
  } else {
    int u = (bid - 2176) * 256 + t;           // 256*512
    int o = u >> 9, i = u & 511;
    u32* d = (u32*)(w3f + (size_t)o * 8192 + i * 16);
    if (isf) {
      const float4* f0 = (const float4*)((const float*)c3 + ((size_t)o * 512 + i) * 8);
      const float4* f1 = (const float4*)((const float*)c3 + (size_t)256 * 512 * 8 + ((size_t)o * 512 + i) * 8);
      #pragma unroll
      for (int j = 0; j < 2; ++j) { float4 v = f0[j]; d[2*j] = packh2(v.x, v.y); d[2*j+1] = packh2(v.z, v.w); }
      #pragma unroll
      for (int j = 0; j < 2; ++j) { float4 v = f1[j]; d[4+2*j] = packh2(v.x, v.y); d[4+2*j+1] = packh2(v.z, v.w); }
    } else {
      const u16* s0 = (const u16*)c3 + ((size_t)o * 512 + i) * 8;
      const u16* s1 = (const u16*)c3 + (size_t)256 * 512 * 8 + ((size_t)o * 512 + i) * 8;
      #pragma unroll
      for (int j = 0; j < 4; ++j) d[j]   = packh2(bf2f(s0[2*j]), bf2f(s0[2*j+1]));
      #pragma unroll
      for (int j = 0; j < 4; ++j) d[4+j] = packh2(bf2f(s1[2*j]), bf2f(s1[2*j+1]));
    }
  }
}

// ---------------------------------------------------------------------------
// Kernel 1: h = x @ W1^T + b1 via split-bf16 (K=768), fp32 out + sum/sumsq.
// Tile 128n x 64o, grid (32,8).
// ---------------------------------------------------------------------------
#define L1_LD 136
__global__ __launch_bounds__(256) void l1_kernel(
    const u16* __restrict__ xs, const u16* __restrict__ w1s, const void* __restrict__ b1,
    const int* __restrict__ flag, float* __restrict__ H, float2* __restrict__ PT)
{
  __shared__ u16 sA[128 * L1_LD];
  __shared__ u16 sB[64 * L1_LD];
  __shared__ float redbuf[8];
  const int n0 = blockIdx.x * 128, o0 = blockIdx.y * 64;
  const int t = threadIdx.x, wave = t >> 6, lane = t & 63, quad = lane >> 4, l16 = lane & 15;
  const int isf = *flag;
  f32x4 acc[2][4] = {};
  for (int ks = 0; ks < 768; ks += 128) {
    #pragma unroll
    for (int r = 0; r < 8; ++r) {
      int idx = t + r * 256;
      int row = idx >> 4, col = idx & 15;
      const uint4* src = (const uint4*)(xs + (size_t)(n0 + row) * 768 + ks) + col;
      *(uint4*)&sA[row * L1_LD + col * 8] = *src;
    }
    #pragma unroll
    for (int r = 0; r < 4; ++r) {
      int idx = t + r * 256;
      int row = idx >> 4, col = idx & 15;
      const uint4* src = (const uint4*)(w1s + (size_t)(o0 + row) * 768 + ks) + col;
      *(uint4*)&sB[row * L1_LD + col * 8] = *src;
    }
    __syncthreads();
    #pragma unroll
    for (int kk = 0; kk < 128; kk += 32) {
      bf16x8 bfr[4];
      #pragma unroll
      for (int fo = 0; fo < 4; ++fo)
        bfr[fo] = *(const bf16x8*)&sB[(fo * 16 + l16) * L1_LD + kk + quad * 8];
      #pragma unroll
      for (int fm = 0; fm < 2; ++fm) {
        bf16x8 av = *(const bf16x8*)&sA[(wave * 32 + fm * 16 + l16) * L1_LD + kk + quad * 8];
        #pragma unroll
        for (int fo = 0; fo < 4; ++fo)
          acc[fm][fo] = __builtin_amdgcn_mfma_f32_16x16x32_bf16(av, bfr[fo], acc[fm][fo], 0, 0, 0);
      }
    }
    __syncthreads();
  }
  float s = 0.f, sq = 0.f;
  #pragma unroll
  for (int fm = 0; fm < 2; ++fm)
  #pragma unroll
  for (int fo = 0; fo < 4; ++fo) {
    int o = o0 + fo * 16 + l16;
    float bias = inval(b1, o, isf);
    #pragma unroll
    for (int r = 0; r < 4; ++r) {
      int n = n0 + wave * 32 + fm * 16 + quad * 4 + r;
      float h = acc[fm][fo][r] + bias;
      H[(size_t)n * 512 + o] = h;
      s += h; sq += h * h;
    }
  }
  #pragma unroll
  for (int off = 32; off; off >>= 1) { s += __shfl_down(s, off); sq += __shfl_down(sq, off); }
  if (lane == 0) { redbuf[wave] = s; redbuf[4 + wave] = sq; }
  __syncthreads();
  if (t == 0) {
    float S = redbuf[0] + redbuf[1] + redbuf[2] + redbuf[3];
    float Q = redbuf[4] + redbuf[5] + redbuf[6] + redbuf[7];
    PT[blockIdx.y * 32 + blockIdx.x] = make_float2(S, Q);
  }
}

// ---------------------------------------------------------------------------
// Kernel 2: reduce 256 partials -> mean, rsqrt(var+eps)
// ---------------------------------------------------------------------------
__global__ __launch_bounds__(256) void red_kernel(const float2* __restrict__ PT, float* __restrict__ ST)
{
  __shared__ float sa[4], sb[4];
  const int t = threadIdx.x;
  float2 p = PT[t];
  float s = p.x, q = p.y;
  #pragma unroll
  for (int off = 32; off; off >>= 1) { s += __shfl_down(s, off); q += __shfl_down(q, off); }
  if ((t & 63) == 0) { sa[t >> 6] = s; sb[t >> 6] = q; }
  __syncthreads();
  if (t == 0) {
    float S = sa[0] + sa[1] + sa[2] + sa[3];
    float Q = sb[0] + sb[1] + sb[2] + sb[3];
    const float N = 4096.f * 512.f;
    float mean = S / N;
    float var = Q / N - mean * mean;
    ST[0] = mean;
    ST[1] = rsqrtf(var + 1e-5f);
  }
}

// ---------------------------------------------------------------------------
// Kernel 3: fused BN+ReLU+basis + fp16 GEMM, split-K (kz=2/3), Chebyshev
// recurrence (1 FMA/harmonic), 1-float H prefetch. Tile 64n x 128o. LDS 52224.
// ---------------------------------------------------------------------------
#define K2_LD 136
__global__ __launch_bounds__(256) void kan2_kernel(
    const float* __restrict__ H, const u16* __restrict__ w2f,
    const void* __restrict__ gammap, const void* __restrict__ betap,
    const int* __restrict__ flag, const float* __restrict__ ST,
    float* __restrict__ P, int kzT)
{
  __shared__ u16 sA[64 * K2_LD];
  __shared__ u16 sB[128 * K2_LD];
  const int n0 = blockIdx.x * 64, o0 = blockIdx.y * 128, kz = blockIdx.z;
  const int t = threadIdx.x, wave = t >> 6, lane = t & 63, quad = lane >> 4, l16 = lane & 15;
  const int wm = (wave & 1) * 32, wo = (wave >> 1) * 64;
  const int isf = *flag;
  const float mean = ST[0];
  const float gs = inval(gammap, 0, isf) * ST[1];
  const float beta = inval(betap, 0, isf);
  const int am = t >> 2, ai = t & 3;
  int i0, nst;
  if (kzT == 3) { i0 = (kz == 0) ? 0 : (kz == 1) ? 172 : 344; nst = (kz < 2) ? 43 : 42; }
  else          { i0 = kz * 256; nst = 64; }
  const int brow = t >> 4, bcol = t & 15;
  const u16* bsrc = w2f + (size_t)(o0 + brow) * 16384 + (size_t)i0 * 32 + bcol * 8;
  const float* hsrc = H + (size_t)(n0 + am) * 512 + i0 + ai;
  f32x4 acc[2][4] = {};
  float ph = *hsrc;
  for (int s = 0; s < nst; ++s) {
    // B stage: load->LDS immediately (transient regs only; r6 held-prefetch spilled)
    #pragma unroll
    for (int r = 0; r < 8; ++r) {
      uint4 v = *(const uint4*)(bsrc + (size_t)r * 16 * 16384);
      *(uint4*)&sB[(brow + r * 16) * K2_LD + bcol * 8] = v;
    }
    // A stage: trig via Chebyshev 3-term recurrence
    {
      float a = fmaxf((ph - mean) * gs + beta, 0.f);
      float s1, c1; __sincosf(a, &s1, &c1);
      float t2 = c1 + c1;
      float cg[16], sg[16];
      cg[0] = c1; sg[0] = s1;
      cg[1] = fmaf(t2, c1, -1.f); sg[1] = t2 * s1;
      #pragma unroll
      for (int g = 2; g < 16; ++g) {
        cg[g] = fmaf(t2, cg[g-1], -cg[g-2]);
        sg[g] = fmaf(t2, sg[g-1], -sg[g-2]);
      }
      u32 pk[16];
      #pragma unroll
      for (int j = 0; j < 8; ++j) pk[j] = packh2(cg[2*j], cg[2*j+1]);
      #pragma unroll
      for (int j = 0; j < 8; ++j) pk[8+j] = packh2(sg[2*j], sg[2*j+1]);
      uint4* dst = (uint4*)&sA[am * K2_LD + ai * 32];
      dst[0] = *(uint4*)&pk[0]; dst[1] = *(uint4*)&pk[4];
      dst[2] = *(uint4*)&pk[8]; dst[3] = *(uint4*)&pk[12];
    }
    __syncthreads();
    bsrc += 128; hsrc += 4;
    if (s + 1 < nst) ph = *hsrc;   // 1-VGPR prefetch; latency hides behind MFMA
    #pragma unroll
    for (int kk = 0; kk < 128; kk += 32) {
      half8 bfr[4], afr[2];
      #pragma unroll
      for (int fo = 0; fo < 4; ++fo)
        bfr[fo] = *(const half8*)&sB[(wo + fo * 16 + l16) * K2_LD + kk + quad * 8];
      #pragma unroll
      for (int fm = 0; fm < 2; ++fm)
        afr[fm] = *(const half8*)&sA[(wm + fm * 16 + l16) * K2_LD + kk + quad * 8];
      #pragma unroll
      for (int fm = 0; fm < 2; ++fm)
      #pragma unroll
      for (int fo = 0; fo < 4; ++fo)
        acc[fm][fo] = __builtin_amdgcn_mfma_f32_16x16x32_f16(afr[fm], bfr[fo], acc[fm][fo], 0, 0, 0);
    }
    __syncthreads();
  }
  float* Pk = P + (size_t)kz * (4096 * 512);
  #pragma unroll
  for (int fm = 0; fm < 2; ++fm)
  #pragma unroll
  for (int fo = 0; fo < 4; ++fo) {
    int o = o0 + wo + fo * 16 + l16;
    #pragma unroll
    for (int r = 0; r < 4; ++r) {
      int n = n0 + wm + fm * 16 + quad * 4 + r;
      Pk[(size_t)n * 512 + o] = acc[fm][fo][r];
    }
  }
}

// ---------------------------------------------------------------------------
// Reduce kan2 partials + bias2 -> H2 (kz runtime 2 or 3)
// ---------------------------------------------------------------------------
__global__ __launch_bounds__(256) void reduce2_kernel(
    const float* __restrict__ P, const void* __restrict__ bias2,
    const int* __restrict__ flag, float* __restrict__ H2, int kzT)
{
  int i = blockIdx.x * 256 + threadIdx.x;  // 524288 float4 groups
  const int isf = *flag;
  float4 a = ((const float4*)P)[i];
  float4 b = ((const float4*)(P + (size_t)4096 * 512))[i];
  float rx = a.x + b.x, ry = a.y + b.y, rz = a.z + b.z, rw = a.w + b.w;
  if (kzT == 3) {
    float4 c = ((const float4*)(P + (size_t)2 * 4096 * 512))[i];
    rx += c.x; ry += c.y; rz += c.z; rw += c.w;
  }
  int o = (i * 4) & 511;
  float4 r;
  r.x = rx + inval(bias2, o + 0, isf);
  r.y = ry + inval(bias2, o + 1, isf);
  r.z = rz + inval(bias2, o + 2, isf);
  r.w = rw + inval(bias2, o + 3, isf);
  ((float4*)H2)[i] = r;
}

// ---------------------------------------------------------------------------
// Kernel 4: basis (grid=8) + fp16 GEMM, split-K kz=3, Chebyshev + prefetch.
// Tile 32n x 128o. Grid (128,2,3) = 768 blocks -> 3/CU. LDS 43520.
// i-chunks 176/176/160 (steps of 8: 22/22/20).
// ---------------------------------------------------------------------------
#define K3_LD 136
__global__ __launch_bounds__(256) void kan3_kernel(
    const float* __restrict__ H2, const u16* __restrict__ w3f,
    const int* __restrict__ flag, float* __restrict__ Q)
{
  __shared__ u16 sA[32 * K3_LD];
  __shared__ u16 sB[128 * K3_LD];
  const int n0 = blockIdx.x * 32, o0 = blockIdx.y * 128, kz = blockIdx.z;
  const int t = threadIdx.x, wave = t >> 6, lane = t & 63, quad = lane >> 4, l16 = lane & 15;
  const int wo = wave * 32;
  const int am = t >> 3, ai = t & 7;
  const int i0 = (kz == 0) ? 0 : (kz == 1) ? 176 : 352;
  const int nst = (kz < 2) ? 22 : 20;
  const int brow = t >> 4, bcol = t & 15;
  const u16* bsrc = w3f + (size_t)(o0 + brow) * 8192 + (size_t)i0 * 16 + bcol * 8;
  const float* hsrc = H2 + (size_t)(n0 + am) * 512 + i0 + ai;
  f32x4 acc[2][2] = {};
  float ph = *hsrc;
  for (int s = 0; s < nst; ++s) {
    #pragma unroll
    for (int r = 0; r < 8; ++r) {
      uint4 v = *(const uint4*)(bsrc + (size_t)r * 16 * 8192);
      *(uint4*)&sB[(brow + r * 16) * K3_LD + bcol * 8] = v;
    }
    {
      float s1, c1; __sincosf(ph, &s1, &c1);
      float t2 = c1 + c1;
      float cg[8], sg[8];
      cg[0] = c1; sg[0] = s1;
      cg[1] = fmaf(t2, c1, -1.f); sg[1] = t2 * s1;
      #pragma unroll
      for (int g = 2; g < 8; ++g) {
        cg[g] = fmaf(t2, cg[g-1], -cg[g-2]);
        sg[g] = fmaf(t2, sg[g-1], -sg[g-2]);
      }
      u32 pk[8];
      #pragma unroll
      for (int j = 0; j < 4; ++j) pk[j] = packh2(cg[2*j], cg[2*j+1]);
      #pragma unroll
      for (int j = 0; j < 4; ++j) pk[4+j] = packh2(sg[2*j], sg[2*j+1]);
      uint4* dst = (uint4*)&sA[am * K3_LD + ai * 16];
      dst[0] = *(uint4*)&pk[0]; dst[1] = *(uint4*)&pk[4];
    }
    __syncthreads();
    bsrc += 128; hsrc += 8;
    if (s + 1 < nst) ph = *hsrc;
    #pragma unroll
    for (int kk = 0; kk < 128; kk += 32) {
      half8 bfr[2], afr[2];
      #pragma unroll
      for (int fo = 0; fo < 2; ++fo)
        bfr[fo] = *(const half8*)&sB[(wo + fo * 16 + l16) * K3_LD + kk + quad * 8];
      #pragma unroll
      for (int fm = 0; fm < 2; ++fm)
        afr[fm] = *(const half8*)&sA[(fm * 16 + l16) * K3_LD + kk + quad * 8];
      #pragma unroll
      for (int fm = 0; fm < 2; ++fm)
      #pragma unroll
      for (int fo = 0; fo < 2; ++fo)
        acc[fm][fo] = __builtin_amdgcn_mfma_f32_16x16x32_f16(afr[fm], bfr[fo], acc[fm][fo], 0, 0, 0);
    }
    __syncthreads();
  }
  float* Qk = Q + (size_t)kz * (4096 * 256);
  #pragma unroll
  for (int fm = 0; fm < 2; ++fm)
  #pragma unroll
  for (int fo = 0; fo < 2; ++fo) {
    int o = o0 + wo + fo * 16 + l16;
    #pragma unroll
    for (int r = 0; r < 4; ++r) {
      int n = n0 + fm * 16 + quad * 4 + r;
      Qk[(size_t)n * 256 + o] = acc[fm][fo][r];
    }
  }
}

// ---------------------------------------------------------------------------
// Kernel 5: fused 3-partial reduce + bias3 + row softmax + fp32 store.
// ---------------------------------------------------------------------------
__global__ __launch_bounds__(256) void softmax_kernel(
    const float* __restrict__ Q, const void* __restrict__ bias3,
    const int* __restrict__ flag, float* __restrict__ out)
{
  const int t = threadIdx.x, wave = t >> 6, lane = t & 63;
  const int row = blockIdx.x * 4 + wave;
  const int isf = *flag;
  size_t base = (size_t)row * 256 + lane * 4;
  float4 a = *(const float4*)(Q + base);
  float4 b = *(const float4*)(Q + (size_t)4096 * 256 + base);
  float4 c = *(const float4*)(Q + (size_t)2 * 4096 * 256 + base);
  int o = lane * 4;
  float v0 = a.x + b.x + c.x + inval(bias3, o + 0, isf);
  float v1 = a.y + b.y + c.y + inval(bias3, o + 1, isf);
  float v2 = a.z + b.z + c.z + inval(bias3, o + 2, isf);
  float v3 = a.w + b.w + c.w + inval(bias3, o + 3, isf);
  float m = fmaxf(fmaxf(v0, v1), fmaxf(v2, v3));
  #pragma unroll
  for (int off = 32; off; off >>= 1) m = fmaxf(m, __shfl_xor(m, off));
  float e0 = __expf(v0 - m), e1 = __expf(v1 - m), e2 = __expf(v2 - m), e3 = __expf(v3 - m);
  float s = e0 + e1 + e2 + e3;
  #pragma unroll
  for (int off = 32; off; off >>= 1) s += __shfl_xor(s, off);
  float inv = 1.f / s;
  *(float4*)(out + base) = make_float4(e0 * inv, e1 * inv, e2 * inv, e3 * inv);
}

// ---------------------------------------------------------------------------
extern "C" void kernel_launch(void* const* d_in, const int* in_sizes, int n_in,
                              void* d_out, int out_size, void* d_ws, size_t ws_size,
                              hipStream_t stream)
{
  const void* x     = d_in[0];
  const void* W1    = d_in[1];
  const void* b1    = d_in[2];
  const void* gamma = d_in[3];
  const void* beta  = d_in[4];
  const void* c2    = d_in[5];
  const void* bias2 = d_in[6];
  const void* c3    = d_in[7];
  const void* bias3 = d_in[8];

  // kz for kan2: 3 if workspace permits the 24 MB partials, else 2.
  const int kz2 = (ws_size >= (61ull << 20) + 262144) ? 3 : 2;

  char* ws = (char*)d_ws;
  float*  H    = (float*)(ws + 0);                        // 8 MB [l1 -> kan2]
  float*  H2   = (float*)(ws + (8ull  << 20));            // 8 MB [reduce2 -> kan3]
  u16*    W2F  = (u16*)  (ws + (16ull << 20));            // 16 MB [prep -> kan2]
  u16*    W3F  = (u16*)  (ws + (32ull << 20));            // 4 MB  [prep -> kan3]
  u16*    Xs   = (u16*)  (ws + (36ull << 20));            // 6.3 MB [prep -> l1]
  u16*    W1s  = (u16*)  (ws + (43ull << 20));            // 0.79 MB [prep -> l1]
  float*  P2   = (float*)(ws + (36ull << 20));            // kz2*8 MB [kan2 -> reduce2]
  float*  Q3   = (float*)(ws + (16ull << 20));            // 12 MB [kan3 -> softmax], over dead W2F
  size_t  tail = (kz2 == 3) ? (61ull << 20) : (52ull << 20);
  float2* PT   = (float2*)(ws + tail);                    // 2 KB
  float*  STT  = (float*) (ws + tail + 65536);            // 8 B
  int*    FLAG = (int*)   (ws + tail + 131072);           // 4 B

  prep_all_kernel<<<dim3(2688), dim3(256), 0, stream>>>(x, W1, Xs, W1s, c2, W2F, c3, W3F, FLAG);
  l1_kernel   <<<dim3(32, 8), dim3(256), 0, stream>>>(Xs, W1s, b1, FLAG, H, PT);
  red_kernel  <<<dim3(1),    dim3(256), 0, stream>>>(PT, STT);
  kan2_kernel <<<dim3(64, 4, kz2), dim3(256), 0, stream>>>(H, W2F, gamma, beta, FLAG, STT, P2, kz2);
  reduce2_kernel<<<dim3(2048), dim3(256), 0, stream>>>(P2, bias2, FLAG, H2, kz2);
  kan3_kernel <<<dim3(128, 2, 3), dim3(256), 0, stream>>>(H2, W3F, FLAG, Q3);
  softmax_kernel<<<dim3(1024), dim3(256), 0, stream>>>(Q3, bias3, FLAG, (float*)d_out);
}

// Round 10
// 230.522 us; speedup vs baseline: 2.4932x; 1.1533x over previous
//
#include <hip/hip_runtime.h>
#include <hip/hip_fp16.h>
#include <stdint.h>

typedef unsigned short u16;
typedef unsigned int u32;
typedef long i64;
typedef short bf16x8 __attribute__((ext_vector_type(8)));
typedef float f32x4 __attribute__((ext_vector_type(4)));

#define SCALE_C   1024.f
#define INV_SCALE 0.0009765625f

__device__ __forceinline__ float bf2f(u16 v) { return __uint_as_float(((u32)v) << 16); }

__device__ __forceinline__ u16 f2bf(float a) {
  u32 u = __float_as_uint(a); u += 0x7FFFu + ((u >> 16) & 1u); return (u16)(u >> 16);
}

__device__ __forceinline__ u32 packbf2(float a, float b) {
  u32 ua = __float_as_uint(a); ua += 0x7FFFu + ((ua >> 16) & 1u);
  u32 ub = __float_as_uint(b); ub += 0x7FFFu + ((ub >> 16) & 1u);
  return (ua >> 16) | (ub & 0xFFFF0000u);
}

// 4 floats -> 4 fp8 e4m3 in one dword (2x v_cvt_pk_fp8_f32)
__device__ __forceinline__ u32 packfp8x4(float a, float b, float c, float d) {
  u32 lo = (u32)__builtin_amdgcn_cvt_pk_fp8_f32(a, b, 0, false);
  return (u32)__builtin_amdgcn_cvt_pk_fp8_f32(c, d, (int)lo, true);
}

__device__ __forceinline__ float inval(const void* p, int idx, int isf) {
  return isf ? ((const float*)p)[idx] : bf2f(((const u16*)p)[idx]);
}

// ---------------------------------------------------------------------------
// prep_all: detect dtype + split(x,W1) to bf16-split + coeffs -> fp8 (x1024).
// Grid 2688: [0,1024) x | [1024,1152) W1 | [1152,2176) c2 | [2176,2688) c3.
// ---------------------------------------------------------------------------
__device__ __forceinline__ void split_body(
    const void* __restrict__ src, u16* __restrict__ dst, int i, int isf, int lo_pos)
{
  int row = i >> 6, g = i & 63;
  float v[4];
  if (isf) {
    float4 t = ((const float4*)src)[i];
    v[0] = t.x; v[1] = t.y; v[2] = t.z; v[3] = t.w;
  } else {
    uint2 t = ((const uint2*)src)[i];
    const u16* p = (const u16*)&t;
    v[0] = bf2f(p[0]); v[1] = bf2f(p[1]); v[2] = bf2f(p[2]); v[3] = bf2f(p[3]);
  }
  u16 hi[4]; float lo[4];
  #pragma unroll
  for (int j = 0; j < 4; ++j) { hi[j] = f2bf(v[j]); lo[j] = v[j] - bf2f(hi[j]); }
  u32 hw0 = (u32)hi[0] | ((u32)hi[1] << 16);
  u32 hw1 = (u32)hi[2] | ((u32)hi[3] << 16);
  u32 lw0 = packbf2(lo[0], lo[1]);
  u32 lw1 = packbf2(lo[2], lo[3]);
  u32* base = (u32*)(dst + (size_t)row * 768);
  int c = g * 2;
  base[c] = hw0; base[c + 1] = hw1;
  if (lo_pos == 1) {
    base[128 + c] = lw0; base[128 + c + 1] = lw1;
    base[256 + c] = hw0; base[256 + c + 1] = hw1;
  } else {
    base[128 + c] = hw0; base[128 + c + 1] = hw1;
    base[256 + c] = lw0; base[256 + c + 1] = lw1;
  }
}

__global__ __launch_bounds__(256) void prep_all_kernel(
    const void* __restrict__ x, const void* __restrict__ W1,
    u16* __restrict__ Xs, u16* __restrict__ W1s,
    const void* __restrict__ c2, unsigned char* __restrict__ w2f8,
    const void* __restrict__ c3, unsigned char* __restrict__ w3f8,
    int* __restrict__ flag)
{
  __shared__ int sf[4];
  const int t = threadIdx.x, wave = t >> 6;
  {
    float v = fabsf(bf2f(((const u16*)W1)[t & 127]));
    int bad = !(v < 1e6f);
    unsigned long long b = __ballot(bad);
    if ((t & 63) == 0) sf[wave] = (b != 0ull) ? 1 : 0;
  }
  __syncthreads();
  const int isf = sf[0] | sf[1] | sf[2] | sf[3];
  const int bid = blockIdx.x;
  if (bid == 0 && t == 0) *flag = isf;
  if (bid < 1024) {
    split_body(x, Xs, bid * 256 + t, isf, 1);
  } else if (bid < 1152) {
    split_body(W1, W1s, (bid - 1024) * 256 + t, isf, 2);
  } else if (bid < 2176) {
    int u = (bid - 1152) * 256 + t;           // 512*512 (o,i)
    int o = u >> 9, i = u & 511;
    u32* d = (u32*)(w2f8 + (size_t)o * 16384 + i * 32);
    if (isf) {
      const float4* f0 = (const float4*)((const float*)c2 + ((size_t)o * 512 + i) * 16);
      const float4* f1 = (const float4*)((const float*)c2 + (size_t)512 * 512 * 16 + ((size_t)o * 512 + i) * 16);
      #pragma unroll
      for (int j = 0; j < 4; ++j) { float4 v = f0[j]; d[j]   = packfp8x4(v.x*SCALE_C, v.y*SCALE_C, v.z*SCALE_C, v.w*SCALE_C); }
      #pragma unroll
      for (int j = 0; j < 4; ++j) { float4 v = f1[j]; d[4+j] = packfp8x4(v.x*SCALE_C, v.y*SCALE_C, v.z*SCALE_C, v.w*SCALE_C); }
    } else {
      const u16* s0 = (const u16*)c2 + ((size_t)o * 512 + i) * 16;
      const u16* s1 = (const u16*)c2 + (size_t)512 * 512 * 16 + ((size_t)o * 512 + i) * 16;
      #pragma unroll
      for (int j = 0; j < 4; ++j) d[j]   = packfp8x4(bf2f(s0[4*j])*SCALE_C, bf2f(s0[4*j+1])*SCALE_C, bf2f(s0[4*j+2])*SCALE_C, bf2f(s0[4*j+3])*SCALE_C);
      #pragma unroll
      for (int j = 0; j < 4; ++j) d[4+j] = packfp8x4(bf2f(s1[4*j])*SCALE_C, bf2f(s1[4*j+1])*SCALE_C, bf2f(s1[4*j+2])*SCALE_C, bf2f(s1[4*j+3])*SCALE_C);
    }
  } else {
    int u = (bid - 2176) * 256 + t;           // 256*512 (o,i)
    int o = u >> 9, i = u & 511;
    u32* d = (u32*)(w3f8 + (size_t)o * 8192 + i * 16);
    if (isf) {
      const float4* f0 = (const float4*)((const float*)c3 + ((size_t)o * 512 + i) * 8);
      const float4* f1 = (const float4*)((const float*)c3 + (size_t)256 * 512 * 8 + ((size_t)o * 512 + i) * 8);
      #pragma unroll
      for (int j = 0; j < 2; ++j) { float4 v = f0[j]; d[j]   = packfp8x4(v.x*SCALE_C, v.y*SCALE_C, v.z*SCALE_C, v.w*SCALE_C); }
      #pragma unroll
      for (int j = 0; j < 2; ++j) { float4 v = f1[j]; d[2+j] = packfp8x4(v.x*SCALE_C, v.y*SCALE_C, v.z*SCALE_C, v.w*SCALE_C); }
    } else {
      const u16* s0 = (const u16*)c3 + ((size_t)o * 512 + i) * 8;
      const u16* s1 = (const u16*)c3 + (size_t)256 * 512 * 8 + ((size_t)o * 512 + i) * 8;
      #pragma unroll
      for (int j = 0; j < 2; ++j) d[j]   = packfp8x4(bf2f(s0[4*j])*SCALE_C, bf2f(s0[4*j+1])*SCALE_C, bf2f(s0[4*j+2])*SCALE_C, bf2f(s0[4*j+3])*SCALE_C);
      #pragma unroll
      for (int j = 0; j < 2; ++j) d[2+j] = packfp8x4(bf2f(s1[4*j])*SCALE_C, bf2f(s1[4*j+1])*SCALE_C, bf2f(s1[4*j+2])*SCALE_C, bf2f(s1[4*j+3])*SCALE_C);
    }
  }
}

// ---------------------------------------------------------------------------
// Kernel 1: h = x @ W1^T + b1 via split-bf16 (K=768), fp32 out + sum/sumsq.
// ---------------------------------------------------------------------------
#define L1_LD 136
__global__ __launch_bounds__(256) void l1_kernel(
    const u16* __restrict__ xs, const u16* __restrict__ w1s, const void* __restrict__ b1,
    const int* __restrict__ flag, float* __restrict__ H, float2* __restrict__ PT)
{
  __shared__ u16 sA[128 * L1_LD];
  __shared__ u16 sB[64 * L1_LD];
  __shared__ float redbuf[8];
  const int n0 = blockIdx.x * 128, o0 = blockIdx.y * 64;
  const int t = threadIdx.x, wave = t >> 6, lane = t & 63, quad = lane >> 4, l16 = lane & 15;
  const int isf = *flag;
  f32x4 acc[2][4] = {};
  for (int ks = 0; ks < 768; ks += 128) {
    #pragma unroll
    for (int r = 0; r < 8; ++r) {
      int idx = t + r * 256;
      int row = idx >> 4, col = idx & 15;
      const uint4* src = (const uint4*)(xs + (size_t)(n0 + row) * 768 + ks) + col;
      *(uint4*)&sA[row * L1_LD + col * 8] = *src;
    }
    #pragma unroll
    for (int r = 0; r < 4; ++r) {
      int idx = t + r * 256;
      int row = idx >> 4, col = idx & 15;
      const uint4* src = (const uint4*)(w1s + (size_t)(o0 + row) * 768 + ks) + col;
      *(uint4*)&sB[row * L1_LD + col * 8] = *src;
    }
    __syncthreads();
    #pragma unroll
    for (int kk = 0; kk < 128; kk += 32) {
      bf16x8 bfr[4];
      #pragma unroll
      for (int fo = 0; fo < 4; ++fo)
        bfr[fo] = *(const bf16x8*)&sB[(fo * 16 + l16) * L1_LD + kk + quad * 8];
      #pragma unroll
      for (int fm = 0; fm < 2; ++fm) {
        bf16x8 av = *(const bf16x8*)&sA[(wave * 32 + fm * 16 + l16) * L1_LD + kk + quad * 8];
        #pragma unroll
        for (int fo = 0; fo < 4; ++fo)
          acc[fm][fo] = __builtin_amdgcn_mfma_f32_16x16x32_bf16(av, bfr[fo], acc[fm][fo], 0, 0, 0);
      }
    }
    __syncthreads();
  }
  float s = 0.f, sq = 0.f;
  #pragma unroll
  for (int fm = 0; fm < 2; ++fm)
  #pragma unroll
  for (int fo = 0; fo < 4; ++fo) {
    int o = o0 + fo * 16 + l16;
    float bias = inval(b1, o, isf);
    #pragma unroll
    for (int r = 0; r < 4; ++r) {
      int n = n0 + wave * 32 + fm * 16 + quad * 4 + r;
      float h = acc[fm][fo][r] + bias;
      H[(size_t)n * 512 + o] = h;
      s += h; sq += h * h;
    }
  }
  #pragma unroll
  for (int off = 32; off; off >>= 1) { s += __shfl_down(s, off); sq += __shfl_down(sq, off); }
  if (lane == 0) { redbuf[wave] = s; redbuf[4 + wave] = sq; }
  __syncthreads();
  if (t == 0) {
    float S = redbuf[0] + redbuf[1] + redbuf[2] + redbuf[3];
    float Q = redbuf[4] + redbuf[5] + redbuf[6] + redbuf[7];
    PT[blockIdx.y * 32 + blockIdx.x] = make_float2(S, Q);
  }
}

__global__ __launch_bounds__(256) void red_kernel(const float2* __restrict__ PT, float* __restrict__ ST)
{
  __shared__ float sa[4], sb[4];
  const int t = threadIdx.x;
  float2 p = PT[t];
  float s = p.x, q = p.y;
  #pragma unroll
  for (int off = 32; off; off >>= 1) { s += __shfl_down(s, off); q += __shfl_down(q, off); }
  if ((t & 63) == 0) { sa[t >> 6] = s; sb[t >> 6] = q; }
  __syncthreads();
  if (t == 0) {
    float S = sa[0] + sa[1] + sa[2] + sa[3];
    float Q = sb[0] + sb[1] + sb[2] + sb[3];
    const float N = 4096.f * 512.f;
    float mean = S / N;
    float var = Q / N - mean * mean;
    ST[0] = mean;
    ST[1] = rsqrtf(var + 1e-5f);
  }
}

// ---------------------------------------------------------------------------
// Kernel 3: BN+ReLU+basis + FP8 MFMA GEMM, generic split-K.
// Tile 64n x 128o, 4 i/step. LDS rows padded to 144 B (16-aligned, 4-dword
// skew mod 32 -> conflict-free b64 frags). LDS 27648 B -> 5 blocks/CU.
// ---------------------------------------------------------------------------
#define K2_LDB 144
__global__ __launch_bounds__(256) void kan2_kernel(
    const float* __restrict__ H, const unsigned char* __restrict__ w2f8,
    const void* __restrict__ gammap, const void* __restrict__ betap,
    const int* __restrict__ flag, const float* __restrict__ ST,
    float* __restrict__ P, int kzT)
{
  __shared__ unsigned char sA8[64 * K2_LDB];
  __shared__ unsigned char sB8[128 * K2_LDB];
  const int n0 = blockIdx.x * 64, o0 = blockIdx.y * 128, kz = blockIdx.z;
  const int t = threadIdx.x, wave = t >> 6, lane = t & 63, quad = lane >> 4, l16 = lane & 15;
  const int wm = (wave & 1) * 32, wo = (wave >> 1) * 64;
  const int isf = *flag;
  const float mean = ST[0];
  const float gs = inval(gammap, 0, isf) * ST[1];
  const float beta = inval(betap, 0, isf);
  const int am = t >> 2, ai = t & 3;
  // generic split over 128 i-steps (4 i each)
  const int q = 128 / kzT, rr = 128 % kzT;
  const int nst = q + (kz < rr ? 1 : 0);
  const int i0 = (kz * q + (kz < rr ? kz : rr)) * 4;
  // B staging: thread covers rows r0+32p (p=0..3), 16B seg
  const int r0 = t >> 3, seg = t & 7;
  const unsigned char* bsrc = w2f8 + (size_t)(o0 + r0) * 16384 + (size_t)i0 * 32 + seg * 16;
  const float* hsrc = H + (size_t)(n0 + am) * 512 + i0 + ai;
  f32x4 acc[2][4] = {};
  float ph = *hsrc;
  for (int s = 0; s < nst; ++s) {
    #pragma unroll
    for (int p = 0; p < 4; ++p) {
      uint4 v = *(const uint4*)(bsrc + (size_t)p * 32 * 16384);
      *(uint4*)&sB8[(r0 + 32 * p) * K2_LDB + seg * 16] = v;
    }
    {
      float a = fmaxf((ph - mean) * gs + beta, 0.f);
      float s1, c1; __sincosf(a, &s1, &c1);
      float t2 = c1 + c1;
      float cg[16], sg[16];
      cg[0] = c1; sg[0] = s1;
      cg[1] = fmaf(t2, c1, -1.f); sg[1] = t2 * s1;
      #pragma unroll
      for (int g = 2; g < 16; ++g) {
        cg[g] = fmaf(t2, cg[g-1], -cg[g-2]);
        sg[g] = fmaf(t2, sg[g-1], -sg[g-2]);
      }
      u32 pk[8];
      #pragma unroll
      for (int j = 0; j < 4; ++j) pk[j]   = packfp8x4(cg[4*j], cg[4*j+1], cg[4*j+2], cg[4*j+3]);
      #pragma unroll
      for (int j = 0; j < 4; ++j) pk[4+j] = packfp8x4(sg[4*j], sg[4*j+1], sg[4*j+2], sg[4*j+3]);
      uint4* dst = (uint4*)&sA8[am * K2_LDB + ai * 32];
      dst[0] = *(uint4*)&pk[0]; dst[1] = *(uint4*)&pk[4];
    }
    __syncthreads();
    bsrc += 128; hsrc += 4;
    if (s + 1 < nst) ph = *hsrc;
    #pragma unroll
    for (int kk = 0; kk < 128; kk += 32) {
      i64 bfr[4], afr[2];
      #pragma unroll
      for (int fo = 0; fo < 4; ++fo)
        bfr[fo] = *(const i64*)&sB8[(wo + fo * 16 + l16) * K2_LDB + kk + quad * 8];
      #pragma unroll
      for (int fm = 0; fm < 2; ++fm)
        afr[fm] = *(const i64*)&sA8[(wm + fm * 16 + l16) * K2_LDB + kk + quad * 8];
      #pragma unroll
      for (int fm = 0; fm < 2; ++fm)
      #pragma unroll
      for (int fo = 0; fo < 4; ++fo)
        acc[fm][fo] = __builtin_amdgcn_mfma_f32_16x16x32_fp8_fp8(afr[fm], bfr[fo], acc[fm][fo], 0, 0, 0);
    }
    __syncthreads();
  }
  float* Pk = P + (size_t)kz * (4096 * 512);
  #pragma unroll
  for (int fm = 0; fm < 2; ++fm)
  #pragma unroll
  for (int fo = 0; fo < 4; ++fo) {
    int o = o0 + wo + fo * 16 + l16;
    #pragma unroll
    for (int r = 0; r < 4; ++r) {
      int n = n0 + wm + fm * 16 + quad * 4 + r;
      Pk[(size_t)n * 512 + o] = acc[fm][fo][r] * INV_SCALE;
    }
  }
}

// ---------------------------------------------------------------------------
// Reduce kan2 partials + bias2 -> H2 (generic kzT)
// ---------------------------------------------------------------------------
__global__ __launch_bounds__(256) void reduce2_kernel(
    const float* __restrict__ P, const void* __restrict__ bias2,
    const int* __restrict__ flag, float* __restrict__ H2, int kzT)
{
  int i = blockIdx.x * 256 + threadIdx.x;  // 524288 float4 groups
  const int isf = *flag;
  float4 a = ((const float4*)P)[i];
  float rx = a.x, ry = a.y, rz = a.z, rw = a.w;
  for (int k = 1; k < kzT; ++k) {
    float4 b = ((const float4*)(P + (size_t)k * 4096 * 512))[i];
    rx += b.x; ry += b.y; rz += b.z; rw += b.w;
  }
  int o = (i * 4) & 511;
  float4 r;
  r.x = rx + inval(bias2, o + 0, isf);
  r.y = ry + inval(bias2, o + 1, isf);
  r.z = rz + inval(bias2, o + 2, isf);
  r.w = rw + inval(bias2, o + 3, isf);
  ((float4*)H2)[i] = r;
}

// ---------------------------------------------------------------------------
// Kernel 4: basis (grid=8) + FP8 MFMA GEMM, split-K kz=6, 8 i/step.
// Tile 32n x 128o. Grid (128,2,6) = 1536 -> 6/CU. LDS 23040 B.
// ---------------------------------------------------------------------------
#define K3_LDB 144
__global__ __launch_bounds__(256) void kan3_kernel(
    const float* __restrict__ H2, const unsigned char* __restrict__ w3f8,
    const int* __restrict__ flag, float* __restrict__ Q)
{
  __shared__ unsigned char sA8[32 * K3_LDB];
  __shared__ unsigned char sB8[128 * K3_LDB];
  const int n0 = blockIdx.x * 32, o0 = blockIdx.y * 128, kz = blockIdx.z;
  const int t = threadIdx.x, wave = t >> 6, lane = t & 63, quad = lane >> 4, l16 = lane & 15;
  const int wo = wave * 32;
  const int am = t >> 3, ai = t & 7;
  // 64 i-steps (8 i each) over kz=6: 11,11,11,11,10,10
  const int nst = 10 + (kz < 4 ? 1 : 0);
  const int i0 = (kz * 10 + (kz < 4 ? kz : 4)) * 8;
  const int r0 = t >> 3, seg = t & 7;
  const unsigned char* bsrc = w3f8 + (size_t)(o0 + r0) * 8192 + (size_t)i0 * 16 + seg * 16;
  const float* hsrc = H2 + (size_t)(n0 + am) * 512 + i0 + ai;
  f32x4 acc[2][2] = {};
  float ph = *hsrc;
  for (int s = 0; s < nst; ++s) {
    #pragma unroll
    for (int p = 0; p < 4; ++p) {
      uint4 v = *(const uint4*)(bsrc + (size_t)p * 32 * 8192);
      *(uint4*)&sB8[(r0 + 32 * p) * K3_LDB + seg * 16] = v;
    }
    {
      float s1, c1; __sincosf(ph, &s1, &c1);
      float t2 = c1 + c1;
      float cg[8], sg[8];
      cg[0] = c1; sg[0] = s1;
      cg[1] = fmaf(t2, c1, -1.f); sg[1] = t2 * s1;
      #pragma unroll
      for (int g = 2; g < 8; ++g) {
        cg[g] = fmaf(t2, cg[g-1], -cg[g-2]);
        sg[g] = fmaf(t2, sg[g-1], -sg[g-2]);
      }
      u32 pk[4];
      pk[0] = packfp8x4(cg[0], cg[1], cg[2], cg[3]);
      pk[1] = packfp8x4(cg[4], cg[5], cg[6], cg[7]);
      pk[2] = packfp8x4(sg[0], sg[1], sg[2], sg[3]);
      pk[3] = packfp8x4(sg[4], sg[5], sg[6], sg[7]);
      *(uint4*)&sA8[am * K3_LDB + ai * 16] = *(uint4*)&pk[0];
    }
    __syncthreads();
    bsrc += 128; hsrc += 8;
    if (s + 1 < nst) ph = *hsrc;
    #pragma unroll
    for (int kk = 0; kk < 128; kk += 32) {
      i64 bfr[2], afr[2];
      #pragma unroll
      for (int fo = 0; fo < 2; ++fo)
        bfr[fo] = *(const i64*)&sB8[(wo + fo * 16 + l16) * K3_LDB + kk + quad * 8];
      #pragma unroll
      for (int fm = 0; fm < 2; ++fm)
        afr[fm] = *(const i64*)&sA8[(fm * 16 + l16) * K3_LDB + kk + quad * 8];
      #pragma unroll
      for (int fm = 0; fm < 2; ++fm)
      #pragma unroll
      for (int fo = 0; fo < 2; ++fo)
        acc[fm][fo] = __builtin_amdgcn_mfma_f32_16x16x32_fp8_fp8(afr[fm], bfr[fo], acc[fm][fo], 0, 0, 0);
    }
    __syncthreads();
  }
  float* Qk = Q + (size_t)kz * (4096 * 256);
  #pragma unroll
  for (int fm = 0; fm < 2; ++fm)
  #pragma unroll
  for (int fo = 0; fo < 2; ++fo) {
    int o = o0 + wo + fo * 16 + l16;
    #pragma unroll
    for (int r = 0; r < 4; ++r) {
      int n = n0 + fm * 16 + quad * 4 + r;
      Qk[(size_t)n * 256 + o] = acc[fm][fo][r] * INV_SCALE;
    }
  }
}

// ---------------------------------------------------------------------------
// Kernel 5: fused 6-partial reduce + bias3 + row softmax + fp32 store.
// ---------------------------------------------------------------------------
__global__ __launch_bounds__(256) void softmax_kernel(
    const float* __restrict__ Q, const void* __restrict__ bias3,
    const int* __restrict__ flag, float* __restrict__ out)
{
  const int t = threadIdx.x, wave = t >> 6, lane = t & 63;
  const int row = blockIdx.x * 4 + wave;
  const int isf = *flag;
  size_t base = (size_t)row * 256 + lane * 4;
  float v0 = 0.f, v1 = 0.f, v2 = 0.f, v3 = 0.f;
  #pragma unroll
  for (int k = 0; k < 6; ++k) {
    float4 a = *(const float4*)(Q + (size_t)k * 4096 * 256 + base);
    v0 += a.x; v1 += a.y; v2 += a.z; v3 += a.w;
  }
  int o = lane * 4;
  v0 += inval(bias3, o + 0, isf);
  v1 += inval(bias3, o + 1, isf);
  v2 += inval(bias3, o + 2, isf);
  v3 += inval(bias3, o + 3, isf);
  float m = fmaxf(fmaxf(v0, v1), fmaxf(v2, v3));
  #pragma unroll
  for (int off = 32; off; off >>= 1) m = fmaxf(m, __shfl_xor(m, off));
  float e0 = __expf(v0 - m), e1 = __expf(v1 - m), e2 = __expf(v2 - m), e3 = __expf(v3 - m);
  float s = e0 + e1 + e2 + e3;
  #pragma unroll
  for (int off = 32; off; off >>= 1) s += __shfl_xor(s, off);
  float inv = 1.f / s;
  *(float4*)(out + base) = make_float4(e0 * inv, e1 * inv, e2 * inv, e3 * inv);
}

// ---------------------------------------------------------------------------
extern "C" void kernel_launch(void* const* d_in, const int* in_sizes, int n_in,
                              void* d_out, int out_size, void* d_ws, size_t ws_size,
                              hipStream_t stream)
{
  const void* x     = d_in[0];
  const void* W1    = d_in[1];
  const void* b1    = d_in[2];
  const void* gamma = d_in[3];
  const void* beta  = d_in[4];
  const void* c2    = d_in[5];
  const void* bias2 = d_in[6];
  const void* c3    = d_in[7];
  const void* bias3 = d_in[8];

  // kan2 split-K: 5 ways if workspace fits 40 MB partials, else 3 (proven).
  const int kz2 = (ws_size >= (75ull << 20)) ? 5 : 3;

  char* ws = (char*)d_ws;
  float*          H    = (float*)(ws + 0);                 // 8 MB [l1 -> kan2]
  float*          H2   = (float*)(ws + (8ull  << 20));     // 8 MB [reduce2 -> kan3]
  unsigned char*  W2F8 = (unsigned char*)(ws + (16ull << 20)); // 8 MB fp8 [prep -> kan2]
  unsigned char*  W3F8 = (unsigned char*)(ws + (24ull << 20)); // 2 MB fp8 [prep -> kan3]
  u16*            Xs   = (u16*)(ws + (26ull << 20));       // 6.3 MB [prep -> l1]
  u16*            W1s  = (u16*)(ws + (33ull << 20));       // 0.79 MB [prep -> l1]
  float*          P2   = (float*)(ws + (34ull << 20));     // kz2*8 MB [kan2 -> reduce2] (over dead Xs? no: after l1)
  float*          Q3   = (float*)(ws + (34ull << 20));     // 24 MB [kan3 -> softmax] (over dead P2)
  size_t tail = (kz2 == 5) ? ((74ull << 20) + 524288) : (58ull << 20);
  float2* PT   = (float2*)(ws + tail);
  float*  STT  = (float*) (ws + tail + 65536);
  int*    FLAG = (int*)   (ws + tail + 131072);

  prep_all_kernel<<<dim3(2688), dim3(256), 0, stream>>>(x, W1, Xs, W1s, c2, W2F8, c3, W3F8, FLAG);
  l1_kernel   <<<dim3(32, 8), dim3(256), 0, stream>>>(Xs, W1s, b1, FLAG, H, PT);
  red_kernel  <<<dim3(1),    dim3(256), 0, stream>>>(PT, STT);
  kan2_kernel <<<dim3(64, 4, kz2), dim3(256), 0, stream>>>(H, W2F8, gamma, beta, FLAG, STT, P2, kz2);
  reduce2_kernel<<<dim3(2048), dim3(256), 0, stream>>>(P2, bias2, FLAG, H2, kz2);
  kan3_kernel <<<dim3(128, 2, 6), dim3(256), 0, stream>>>(H2, W3F8, FLAG, Q3);
  softmax_kernel<<<dim3(1024), dim3(256), 0, stream>>>(Q3, bias3, FLAG, (float*)d_out);
}

// Round 11
// 227.645 us; speedup vs baseline: 2.5247x; 1.0126x over previous
//
#include <hip/hip_runtime.h>
#include <hip/hip_fp16.h>
#include <stdint.h>

typedef unsigned short u16;
typedef unsigned int u32;
typedef long i64;
typedef short bf16x8 __attribute__((ext_vector_type(8)));
typedef float f32x4 __attribute__((ext_vector_type(4)));

#define SCALE_C   1024.f
#define INV_SCALE 0.0009765625f

__device__ __forceinline__ float bf2f(u16 v) { return __uint_as_float(((u32)v) << 16); }

__device__ __forceinline__ u16 f2bf(float a) {
  u32 u = __float_as_uint(a); u += 0x7FFFu + ((u >> 16) & 1u); return (u16)(u >> 16);
}

__device__ __forceinline__ u32 packbf2(float a, float b) {
  u32 ua = __float_as_uint(a); ua += 0x7FFFu + ((ua >> 16) & 1u);
  u32 ub = __float_as_uint(b); ub += 0x7FFFu + ((ub >> 16) & 1u);
  return (ua >> 16) | (ub & 0xFFFF0000u);
}

// 4 floats -> 4 fp8 e4m3 in one dword (2x v_cvt_pk_fp8_f32)
__device__ __forceinline__ u32 packfp8x4(float a, float b, float c, float d) {
  u32 lo = (u32)__builtin_amdgcn_cvt_pk_fp8_f32(a, b, 0, false);
  return (u32)__builtin_amdgcn_cvt_pk_fp8_f32(c, d, (int)lo, true);
}

__device__ __forceinline__ float inval(const void* p, int idx, int isf) {
  return isf ? ((const float*)p)[idx] : bf2f(((const u16*)p)[idx]);
}

// ---------------------------------------------------------------------------
// prep_all: detect dtype + split(x,W1) to bf16-split + coeffs -> fp8 (x1024).
// Grid 2688: [0,1024) x | [1024,1152) W1 | [1152,2176) c2 | [2176,2688) c3.
// ---------------------------------------------------------------------------
__device__ __forceinline__ void split_body(
    const void* __restrict__ src, u16* __restrict__ dst, int i, int isf, int lo_pos)
{
  int row = i >> 6, g = i & 63;
  float v[4];
  if (isf) {
    float4 t = ((const float4*)src)[i];
    v[0] = t.x; v[1] = t.y; v[2] = t.z; v[3] = t.w;
  } else {
    uint2 t = ((const uint2*)src)[i];
    const u16* p = (const u16*)&t;
    v[0] = bf2f(p[0]); v[1] = bf2f(p[1]); v[2] = bf2f(p[2]); v[3] = bf2f(p[3]);
  }
  u16 hi[4]; float lo[4];
  #pragma unroll
  for (int j = 0; j < 4; ++j) { hi[j] = f2bf(v[j]); lo[j] = v[j] - bf2f(hi[j]); }
  u32 hw0 = (u32)hi[0] | ((u32)hi[1] << 16);
  u32 hw1 = (u32)hi[2] | ((u32)hi[3] << 16);
  u32 lw0 = packbf2(lo[0], lo[1]);
  u32 lw1 = packbf2(lo[2], lo[3]);
  u32* base = (u32*)(dst + (size_t)row * 768);
  int c = g * 2;
  base[c] = hw0; base[c + 1] = hw1;
  if (lo_pos == 1) {
    base[128 + c] = lw0; base[128 + c + 1] = lw1;
    base[256 + c] = hw0; base[256 + c + 1] = hw1;
  } else {
    base[128 + c] = hw0; base[128 + c + 1] = hw1;
    base[256 + c] = lw0; base[256 + c + 1] = lw1;
  }
}

__global__ __launch_bounds__(256) void prep_all_kernel(
    const void* __restrict__ x, const void* __restrict__ W1,
    u16* __restrict__ Xs, u16* __restrict__ W1s,
    const void* __restrict__ c2, unsigned char* __restrict__ w2f8,
    const void* __restrict__ c3, unsigned char* __restrict__ w3f8,
    int* __restrict__ flag)
{
  __shared__ int sf[4];
  const int t = threadIdx.x, wave = t >> 6;
  {
    float v = fabsf(bf2f(((const u16*)W1)[t & 127]));
    int bad = !(v < 1e6f);
    unsigned long long b = __ballot(bad);
    if ((t & 63) == 0) sf[wave] = (b != 0ull) ? 1 : 0;
  }
  __syncthreads();
  const int isf = sf[0] | sf[1] | sf[2] | sf[3];
  const int bid = blockIdx.x;
  if (bid == 0 && t == 0) *flag = isf;
  if (bid < 1024) {
    split_body(x, Xs, bid * 256 + t, isf, 1);
  } else if (bid < 1152) {
    split_body(W1, W1s, (bid - 1024) * 256 + t, isf, 2);
  } else if (bid < 2176) {
    int u = (bid - 1152) * 256 + t;           // 512*512 (o,i)
    int o = u >> 9, i = u & 511;
    u32* d = (u32*)(w2f8 + (size_t)o * 16384 + i * 32);
    if (isf) {
      const float4* f0 = (const float4*)((const float*)c2 + ((size_t)o * 512 + i) * 16);
      const float4* f1 = (const float4*)((const float*)c2 + (size_t)512 * 512 * 16 + ((size_t)o * 512 + i) * 16);
      #pragma unroll
      for (int j = 0; j < 4; ++j) { float4 v = f0[j]; d[j]   = packfp8x4(v.x*SCALE_C, v.y*SCALE_C, v.z*SCALE_C, v.w*SCALE_C); }
      #pragma unroll
      for (int j = 0; j < 4; ++j) { float4 v = f1[j]; d[4+j] = packfp8x4(v.x*SCALE_C, v.y*SCALE_C, v.z*SCALE_C, v.w*SCALE_C); }
    } else {
      const u16* s0 = (const u16*)c2 + ((size_t)o * 512 + i) * 16;
      const u16* s1 = (const u16*)c2 + (size_t)512 * 512 * 16 + ((size_t)o * 512 + i) * 16;
      #pragma unroll
      for (int j = 0; j < 4; ++j) d[j]   = packfp8x4(bf2f(s0[4*j])*SCALE_C, bf2f(s0[4*j+1])*SCALE_C, bf2f(s0[4*j+2])*SCALE_C, bf2f(s0[4*j+3])*SCALE_C);
      #pragma unroll
      for (int j = 0; j < 4; ++j) d[4+j] = packfp8x4(bf2f(s1[4*j])*SCALE_C, bf2f(s1[4*j+1])*SCALE_C, bf2f(s1[4*j+2])*SCALE_C, bf2f(s1[4*j+3])*SCALE_C);
    }
  } else {
    int u = (bid - 2176) * 256 + t;           // 256*512 (o,i)
    int o = u >> 9, i = u & 511;
    u32* d = (u32*)(w3f8 + (size_t)o * 8192 + i * 16);
    if (isf) {
      const float4* f0 = (const float4*)((const float*)c3 + ((size_t)o * 512 + i) * 8);
      const float4* f1 = (const float4*)((const float*)c3 + (size_t)256 * 512 * 8 + ((size_t)o * 512 + i) * 8);
      #pragma unroll
      for (int j = 0; j < 2; ++j) { float4 v = f0[j]; d[j]   = packfp8x4(v.x*SCALE_C, v.y*SCALE_C, v.z*SCALE_C, v.w*SCALE_C); }
      #pragma unroll
      for (int j = 0; j < 2; ++j) { float4 v = f1[j]; d[2+j] = packfp8x4(v.x*SCALE_C, v.y*SCALE_C, v.z*SCALE_C, v.w*SCALE_C); }
    } else {
      const u16* s0 = (const u16*)c3 + ((size_t)o * 512 + i) * 8;
      const u16* s1 = (const u16*)c3 + (size_t)256 * 512 * 8 + ((size_t)o * 512 + i) * 8;
      #pragma unroll
      for (int j = 0; j < 2; ++j) d[j]   = packfp8x4(bf2f(s0[4*j])*SCALE_C, bf2f(s0[4*j+1])*SCALE_C, bf2f(s0[4*j+2])*SCALE_C, bf2f(s0[4*j+3])*SCALE_C);
      #pragma unroll
      for (int j = 0; j < 2; ++j) d[2+j] = packfp8x4(bf2f(s1[4*j])*SCALE_C, bf2f(s1[4*j+1])*SCALE_C, bf2f(s1[4*j+2])*SCALE_C, bf2f(s1[4*j+3])*SCALE_C);
    }
  }
}

// ---------------------------------------------------------------------------
// Kernel 1: h = x @ W1^T + b1 via split-bf16 (K=768), fp32 out + sum/sumsq.
// ---------------------------------------------------------------------------
#define L1_LD 136
__global__ __launch_bounds__(256) void l1_kernel(
    const u16* __restrict__ xs, const u16* __restrict__ w1s, const void* __restrict__ b1,
    const int* __restrict__ flag, float* __restrict__ H, float2* __restrict__ PT)
{
  __shared__ u16 sA[128 * L1_LD];
  __shared__ u16 sB[64 * L1_LD];
  __shared__ float redbuf[8];
  const int n0 = blockIdx.x * 128, o0 = blockIdx.y * 64;
  const int t = threadIdx.x, wave = t >> 6, lane = t & 63, quad = lane >> 4, l16 = lane & 15;
  const int isf = *flag;
  f32x4 acc[2][4] = {};
  for (int ks = 0; ks < 768; ks += 128) {
    #pragma unroll
    for (int r = 0; r < 8; ++r) {
      int idx = t + r * 256;
      int row = idx >> 4, col = idx & 15;
      const uint4* src = (const uint4*)(xs + (size_t)(n0 + row) * 768 + ks) + col;
      *(uint4*)&sA[row * L1_LD + col * 8] = *src;
    }
    #pragma unroll
    for (int r = 0; r < 4; ++r) {
      int idx = t + r * 256;
      int row = idx >> 4, col = idx & 15;
      const uint4* src = (const uint4*)(w1s + (size_t)(o0 + row) * 768 + ks) + col;
      *(uint4*)&sB[row * L1_LD + col * 8] = *src;
    }
    __syncthreads();
    #pragma unroll
    for (int kk = 0; kk < 128; kk += 32) {
      bf16x8 bfr[4];
      #pragma unroll
      for (int fo = 0; fo < 4; ++fo)
        bfr[fo] = *(const bf16x8*)&sB[(fo * 16 + l16) * L1_LD + kk + quad * 8];
      #pragma unroll
      for (int fm = 0; fm < 2; ++fm) {
        bf16x8 av = *(const bf16x8*)&sA[(wave * 32 + fm * 16 + l16) * L1_LD + kk + quad * 8];
        #pragma unroll
        for (int fo = 0; fo < 4; ++fo)
          acc[fm][fo] = __builtin_amdgcn_mfma_f32_16x16x32_bf16(av, bfr[fo], acc[fm][fo], 0, 0, 0);
      }
    }
    __syncthreads();
  }
  float s = 0.f, sq = 0.f;
  #pragma unroll
  for (int fm = 0; fm < 2; ++fm)
  #pragma unroll
  for (int fo = 0; fo < 4; ++fo) {
    int o = o0 + fo * 16 + l16;
    float bias = inval(b1, o, isf);
    #pragma unroll
    for (int r = 0; r < 4; ++r) {
      int n = n0 + wave * 32 + fm * 16 + quad * 4 + r;
      float h = acc[fm][fo][r] + bias;
      H[(size_t)n * 512 + o] = h;
      s += h; sq += h * h;
    }
  }
  #pragma unroll
  for (int off = 32; off; off >>= 1) { s += __shfl_down(s, off); sq += __shfl_down(sq, off); }
  if (lane == 0) { redbuf[wave] = s; redbuf[4 + wave] = sq; }
  __syncthreads();
  if (t == 0) {
    float S = redbuf[0] + redbuf[1] + redbuf[2] + redbuf[3];
    float Q = redbuf[4] + redbuf[5] + redbuf[6] + redbuf[7];
    PT[blockIdx.y * 32 + blockIdx.x] = make_float2(S, Q);
  }
}

// ---------------------------------------------------------------------------
// Kernel 3: BN+ReLU+basis + FP8 MFMA GEMM, generic split-K.
// BN stats computed per-block from the 256 l1 partials (red_kernel fused).
// Tile 64n x 128o, 4 i/step. LDS 27648 B -> 5 blocks/CU.
// ---------------------------------------------------------------------------
#define K2_LDB 144
__global__ __launch_bounds__(256) void kan2_kernel(
    const float* __restrict__ H, const unsigned char* __restrict__ w2f8,
    const void* __restrict__ gammap, const void* __restrict__ betap,
    const int* __restrict__ flag, const float2* __restrict__ PT,
    float* __restrict__ P, int kzT)
{
  __shared__ unsigned char sA8[64 * K2_LDB];
  __shared__ unsigned char sB8[128 * K2_LDB];
  __shared__ float sred[8];
  const int n0 = blockIdx.x * 64, o0 = blockIdx.y * 128, kz = blockIdx.z;
  const int t = threadIdx.x, wave = t >> 6, lane = t & 63, quad = lane >> 4, l16 = lane & 15;
  const int wm = (wave & 1) * 32, wo = (wave >> 1) * 64;
  const int isf = *flag;
  // fused red_kernel: block-local reduction of the 256 l1 partials
  {
    float2 p = PT[t];
    float s = p.x, q = p.y;
    #pragma unroll
    for (int off = 32; off; off >>= 1) { s += __shfl_down(s, off); q += __shfl_down(q, off); }
    if (lane == 0) { sred[wave] = s; sred[4 + wave] = q; }
  }
  __syncthreads();
  const float Ssum = sred[0] + sred[1] + sred[2] + sred[3];
  const float Qsum = sred[4] + sred[5] + sred[6] + sred[7];
  const float Nn = 4096.f * 512.f;
  const float mean = Ssum / Nn;
  const float rstd = rsqrtf(Qsum / Nn - mean * mean + 1e-5f);
  const float gs = inval(gammap, 0, isf) * rstd;
  const float beta = inval(betap, 0, isf);
  const int am = t >> 2, ai = t & 3;
  const int q = 128 / kzT, rr = 128 % kzT;
  const int nst = q + (kz < rr ? 1 : 0);
  const int i0 = (kz * q + (kz < rr ? kz : rr)) * 4;
  const int r0 = t >> 3, seg = t & 7;
  const unsigned char* bsrc = w2f8 + (size_t)(o0 + r0) * 16384 + (size_t)i0 * 32 + seg * 16;
  const float* hsrc = H + (size_t)(n0 + am) * 512 + i0 + ai;
  f32x4 acc[2][4] = {};
  float ph = *hsrc;
  for (int s = 0; s < nst; ++s) {
    #pragma unroll
    for (int p = 0; p < 4; ++p) {
      uint4 v = *(const uint4*)(bsrc + (size_t)p * 32 * 16384);
      *(uint4*)&sB8[(r0 + 32 * p) * K2_LDB + seg * 16] = v;
    }
    {
      float a = fmaxf((ph - mean) * gs + beta, 0.f);
      float s1, c1; __sincosf(a, &s1, &c1);
      float t2 = c1 + c1;
      float cg[16], sg[16];
      cg[0] = c1; sg[0] = s1;
      cg[1] = fmaf(t2, c1, -1.f); sg[1] = t2 * s1;
      #pragma unroll
      for (int g = 2; g < 16; ++g) {
        cg[g] = fmaf(t2, cg[g-1], -cg[g-2]);
        sg[g] = fmaf(t2, sg[g-1], -sg[g-2]);
      }
      u32 pk[8];
      #pragma unroll
      for (int j = 0; j < 4; ++j) pk[j]   = packfp8x4(cg[4*j], cg[4*j+1], cg[4*j+2], cg[4*j+3]);
      #pragma unroll
      for (int j = 0; j < 4; ++j) pk[4+j] = packfp8x4(sg[4*j], sg[4*j+1], sg[4*j+2], sg[4*j+3]);
      uint4* dst = (uint4*)&sA8[am * K2_LDB + ai * 32];
      dst[0] = *(uint4*)&pk[0]; dst[1] = *(uint4*)&pk[4];
    }
    __syncthreads();
    bsrc += 128; hsrc += 4;
    if (s + 1 < nst) ph = *hsrc;
    #pragma unroll
    for (int kk = 0; kk < 128; kk += 32) {
      i64 bfr[4], afr[2];
      #pragma unroll
      for (int fo = 0; fo < 4; ++fo)
        bfr[fo] = *(const i64*)&sB8[(wo + fo * 16 + l16) * K2_LDB + kk + quad * 8];
      #pragma unroll
      for (int fm = 0; fm < 2; ++fm)
        afr[fm] = *(const i64*)&sA8[(wm + fm * 16 + l16) * K2_LDB + kk + quad * 8];
      #pragma unroll
      for (int fm = 0; fm < 2; ++fm)
      #pragma unroll
      for (int fo = 0; fo < 4; ++fo)
        acc[fm][fo] = __builtin_amdgcn_mfma_f32_16x16x32_fp8_fp8(afr[fm], bfr[fo], acc[fm][fo], 0, 0, 0);
    }
    __syncthreads();
  }
  float* Pk = P + (size_t)kz * (4096 * 512);
  #pragma unroll
  for (int fm = 0; fm < 2; ++fm)
  #pragma unroll
  for (int fo = 0; fo < 4; ++fo) {
    int o = o0 + wo + fo * 16 + l16;
    #pragma unroll
    for (int r = 0; r < 4; ++r) {
      int n = n0 + wm + fm * 16 + quad * 4 + r;
      Pk[(size_t)n * 512 + o] = acc[fm][fo][r] * INV_SCALE;
    }
  }
}

// ---------------------------------------------------------------------------
// Kernel 4: basis (grid=8) + FP8 MFMA GEMM, split-K kz=6, 8 i/step.
// reduce2 fused: h2 = sum_k P2[k] + bias2 computed inline (prefetched).
// Tile 32n x 128o. Grid (128,2,6) = 1536 -> 6/CU. LDS 23040 B.
// ---------------------------------------------------------------------------
#define K3_LDB 144
__global__ __launch_bounds__(256) void kan3_kernel(
    const float* __restrict__ P2, const void* __restrict__ bias2,
    const unsigned char* __restrict__ w3f8,
    const int* __restrict__ flag, float* __restrict__ Q, int kzT2)
{
  __shared__ unsigned char sA8[32 * K3_LDB];
  __shared__ unsigned char sB8[128 * K3_LDB];
  const int n0 = blockIdx.x * 32, o0 = blockIdx.y * 128, kz = blockIdx.z;
  const int t = threadIdx.x, wave = t >> 6, lane = t & 63, quad = lane >> 4, l16 = lane & 15;
  const int wo = wave * 32;
  const int am = t >> 3, ai = t & 7;
  const int nst = 10 + (kz < 4 ? 1 : 0);
  const int i0 = (kz * 10 + (kz < 4 ? kz : 4)) * 8;
  const int r0 = t >> 3, seg = t & 7;
  const int isf = *flag;
  const unsigned char* bsrc = w3f8 + (size_t)(o0 + r0) * 8192 + (size_t)i0 * 16 + seg * 16;
  const float* psrc = P2 + (size_t)(n0 + am) * 512 + i0 + ai;
  f32x4 acc[2][2] = {};
  // fused reduce2: h2 element = sum of kzT2 partials + bias2
  float ph;
  {
    float v = inval(bias2, i0 + ai, isf);
    for (int k = 0; k < kzT2; ++k) v += psrc[(size_t)k * 4096 * 512];
    ph = v;
  }
  for (int s = 0; s < nst; ++s) {
    #pragma unroll
    for (int p = 0; p < 4; ++p) {
      uint4 v = *(const uint4*)(bsrc + (size_t)p * 32 * 8192);
      *(uint4*)&sB8[(r0 + 32 * p) * K3_LDB + seg * 16] = v;
    }
    {
      float s1, c1; __sincosf(ph, &s1, &c1);
      float t2 = c1 + c1;
      float cg[8], sg[8];
      cg[0] = c1; sg[0] = s1;
      cg[1] = fmaf(t2, c1, -1.f); sg[1] = t2 * s1;
      #pragma unroll
      for (int g = 2; g < 8; ++g) {
        cg[g] = fmaf(t2, cg[g-1], -cg[g-2]);
        sg[g] = fmaf(t2, sg[g-1], -sg[g-2]);
      }
      u32 pk[4];
      pk[0] = packfp8x4(cg[0], cg[1], cg[2], cg[3]);
      pk[1] = packfp8x4(cg[4], cg[5], cg[6], cg[7]);
      pk[2] = packfp8x4(sg[0], sg[1], sg[2], sg[3]);
      pk[3] = packfp8x4(sg[4], sg[5], sg[6], sg[7]);
      *(uint4*)&sA8[am * K3_LDB + ai * 16] = *(uint4*)&pk[0];
    }
    __syncthreads();
    bsrc += 128; psrc += 8;
    if (s + 1 < nst) {
      float v = inval(bias2, i0 + (s + 1) * 8 + ai, isf);
      for (int k = 0; k < kzT2; ++k) v += psrc[(size_t)k * 4096 * 512];
      ph = v;
    }
    #pragma unroll
    for (int kk = 0; kk < 128; kk += 32) {
      i64 bfr[2], afr[2];
      #pragma unroll
      for (int fo = 0; fo < 2; ++fo)
        bfr[fo] = *(const i64*)&sB8[(wo + fo * 16 + l16) * K3_LDB + kk + quad * 8];
      #pragma unroll
      for (int fm = 0; fm < 2; ++fm)
        afr[fm] = *(const i64*)&sA8[(fm * 16 + l16) * K3_LDB + kk + quad * 8];
      #pragma unroll
      for (int fm = 0; fm < 2; ++fm)
      #pragma unroll
      for (int fo = 0; fo < 2; ++fo)
        acc[fm][fo] = __builtin_amdgcn_mfma_f32_16x16x32_fp8_fp8(afr[fm], bfr[fo], acc[fm][fo], 0, 0, 0);
    }
    __syncthreads();
  }
  float* Qk = Q + (size_t)kz * (4096 * 256);
  #pragma unroll
  for (int fm = 0; fm < 2; ++fm)
  #pragma unroll
  for (int fo = 0; fo < 2; ++fo) {
    int o = o0 + wo + fo * 16 + l16;
    #pragma unroll
    for (int r = 0; r < 4; ++r) {
      int n = n0 + fm * 16 + quad * 4 + r;
      Qk[(size_t)n * 256 + o] = acc[fm][fo][r] * INV_SCALE;
    }
  }
}

// ---------------------------------------------------------------------------
// Kernel 5: fused 6-partial reduce + bias3 + row softmax + fp32 store.
// ---------------------------------------------------------------------------
__global__ __launch_bounds__(256) void softmax_kernel(
    const float* __restrict__ Q, const void* __restrict__ bias3,
    const int* __restrict__ flag, float* __restrict__ out)
{
  const int t = threadIdx.x, wave = t >> 6, lane = t & 63;
  const int row = blockIdx.x * 4 + wave;
  const int isf = *flag;
  size_t base = (size_t)row * 256 + lane * 4;
  float v0 = 0.f, v1 = 0.f, v2 = 0.f, v3 = 0.f;
  #pragma unroll
  for (int k = 0; k < 6; ++k) {
    float4 a = *(const float4*)(Q + (size_t)k * 4096 * 256 + base);
    v0 += a.x; v1 += a.y; v2 += a.z; v3 += a.w;
  }
  int o = lane * 4;
  v0 += inval(bias3, o + 0, isf);
  v1 += inval(bias3, o + 1, isf);
  v2 += inval(bias3, o + 2, isf);
  v3 += inval(bias3, o + 3, isf);
  float m = fmaxf(fmaxf(v0, v1), fmaxf(v2, v3));
  #pragma unroll
  for (int off = 32; off; off >>= 1) m = fmaxf(m, __shfl_xor(m, off));
  float e0 = __expf(v0 - m), e1 = __expf(v1 - m), e2 = __expf(v2 - m), e3 = __expf(v3 - m);
  float s = e0 + e1 + e2 + e3;
  #pragma unroll
  for (int off = 32; off; off >>= 1) s += __shfl_xor(s, off);
  float inv = 1.f / s;
  *(float4*)(out + base) = make_float4(e0 * inv, e1 * inv, e2 * inv, e3 * inv);
}

// ---------------------------------------------------------------------------
extern "C" void kernel_launch(void* const* d_in, const int* in_sizes, int n_in,
                              void* d_out, int out_size, void* d_ws, size_t ws_size,
                              hipStream_t stream)
{
  const void* x     = d_in[0];
  const void* W1    = d_in[1];
  const void* b1    = d_in[2];
  const void* gamma = d_in[3];
  const void* beta  = d_in[4];
  const void* c2    = d_in[5];
  const void* bias2 = d_in[6];
  const void* c3    = d_in[7];
  const void* bias3 = d_in[8];

  // kan2 split-K: 5 ways if workspace fits 40 MB partials, else 3.
  const int kz2 = (ws_size >= (75ull << 20)) ? 5 : 3;

  char* ws = (char*)d_ws;
  // [0,24):   Q3 (kan3->softmax), laid over dead H [0,8) + dead W2F8 [16,24)
  // [0,8):    H (l1->kan2)
  // [16,24):  W2F8 (prep->kan2)
  // [24,26):  W3F8 (prep->kan3)
  // [26,33):  Xs (prep->l1)
  // [33,34):  W1s (prep->l1)
  // [34,34+8*kz2): P2 (kan2->kan3)
  float*          H    = (float*)(ws + 0);
  unsigned char*  W2F8 = (unsigned char*)(ws + (16ull << 20));
  unsigned char*  W3F8 = (unsigned char*)(ws + (24ull << 20));
  u16*            Xs   = (u16*)(ws + (26ull << 20));
  u16*            W1s  = (u16*)(ws + (33ull << 20));
  float*          P2   = (float*)(ws + (34ull << 20));
  float*          Q3   = (float*)(ws + 0);
  size_t tail = (34ull << 20) + (size_t)kz2 * (8ull << 20) + 524288;
  float2* PT   = (float2*)(ws + tail);
  int*    FLAG = (int*)   (ws + tail + 65536);

  prep_all_kernel<<<dim3(2688), dim3(256), 0, stream>>>(x, W1, Xs, W1s, c2, W2F8, c3, W3F8, FLAG);
  l1_kernel   <<<dim3(32, 8), dim3(256), 0, stream>>>(Xs, W1s, b1, FLAG, H, PT);
  kan2_kernel <<<dim3(64, 4, kz2), dim3(256), 0, stream>>>(H, W2F8, gamma, beta, FLAG, PT, P2, kz2);
  kan3_kernel <<<dim3(128, 2, 6), dim3(256), 0, stream>>>(P2, bias2, W3F8, FLAG, Q3, kz2);
  softmax_kernel<<<dim3(1024), dim3(256), 0, stream>>>(Q3, bias3, FLAG, (float*)d_out);
}

// Round 12
// 219.818 us; speedup vs baseline: 2.6146x; 1.0356x over previous
//
#include <hip/hip_runtime.h>
#include <hip/hip_fp16.h>
#include <stdint.h>

typedef unsigned short u16;
typedef unsigned int u32;
typedef long i64;
typedef short bf16x8 __attribute__((ext_vector_type(8)));
typedef float f32x4 __attribute__((ext_vector_type(4)));

#define SCALE_C   1024.f
#define INV_SCALE 0.0009765625f

__device__ __forceinline__ float bf2f(u16 v) { return __uint_as_float(((u32)v) << 16); }

__device__ __forceinline__ u16 f2bf(float a) {
  u32 u = __float_as_uint(a); u += 0x7FFFu + ((u >> 16) & 1u); return (u16)(u >> 16);
}

__device__ __forceinline__ u32 packbf2(float a, float b) {
  u32 ua = __float_as_uint(a); ua += 0x7FFFu + ((ua >> 16) & 1u);
  u32 ub = __float_as_uint(b); ub += 0x7FFFu + ((ub >> 16) & 1u);
  return (ua >> 16) | (ub & 0xFFFF0000u);
}

// 4 floats -> 4 fp8 e4m3 in one dword (2x v_cvt_pk_fp8_f32)
__device__ __forceinline__ u32 packfp8x4(float a, float b, float c, float d) {
  u32 lo = (u32)__builtin_amdgcn_cvt_pk_fp8_f32(a, b, 0, false);
  return (u32)__builtin_amdgcn_cvt_pk_fp8_f32(c, d, (int)lo, true);
}

__device__ __forceinline__ float inval(const void* p, int idx, int isf) {
  return isf ? ((const float*)p)[idx] : bf2f(((const u16*)p)[idx]);
}

// ---------------------------------------------------------------------------
// prep_all: detect dtype + split(x,W1) to bf16-split + coeffs -> fp8 (x1024).
// ---------------------------------------------------------------------------
__device__ __forceinline__ void split_body(
    const void* __restrict__ src, u16* __restrict__ dst, int i, int isf, int lo_pos)
{
  int row = i >> 6, g = i & 63;
  float v[4];
  if (isf) {
    float4 t = ((const float4*)src)[i];
    v[0] = t.x; v[1] = t.y; v[2] = t.z; v[3] = t.w;
  } else {
    uint2 t = ((const uint2*)src)[i];
    const u16* p = (const u16*)&t;
    v[0] = bf2f(p[0]); v[1] = bf2f(p[1]); v[2] = bf2f(p[2]); v[3] = bf2f(p[3]);
  }
  u16 hi[4]; float lo[4];
  #pragma unroll
  for (int j = 0; j < 4; ++j) { hi[j] = f2bf(v[j]); lo[j] = v[j] - bf2f(hi[j]); }
  u32 hw0 = (u32)hi[0] | ((u32)hi[1] << 16);
  u32 hw1 = (u32)hi[2] | ((u32)hi[3] << 16);
  u32 lw0 = packbf2(lo[0], lo[1]);
  u32 lw1 = packbf2(lo[2], lo[3]);
  u32* base = (u32*)(dst + (size_t)row * 768);
  int c = g * 2;
  base[c] = hw0; base[c + 1] = hw1;
  if (lo_pos == 1) {
    base[128 + c] = lw0; base[128 + c + 1] = lw1;
    base[256 + c] = hw0; base[256 + c + 1] = hw1;
  } else {
    base[128 + c] = hw0; base[128 + c + 1] = hw1;
    base[256 + c] = lw0; base[256 + c + 1] = lw1;
  }
}

__global__ __launch_bounds__(256) void prep_all_kernel(
    const void* __restrict__ x, const void* __restrict__ W1,
    u16* __restrict__ Xs, u16* __restrict__ W1s,
    const void* __restrict__ c2, unsigned char* __restrict__ w2f8,
    const void* __restrict__ c3, unsigned char* __restrict__ w3f8,
    int* __restrict__ flag)
{
  __shared__ int sf[4];
  const int t = threadIdx.x, wave = t >> 6;
  {
    float v = fabsf(bf2f(((const u16*)W1)[t & 127]));
    int bad = !(v < 1e6f);
    unsigned long long b = __ballot(bad);
    if ((t & 63) == 0) sf[wave] = (b != 0ull) ? 1 : 0;
  }
  __syncthreads();
  const int isf = sf[0] | sf[1] | sf[2] | sf[3];
  const int bid = blockIdx.x;
  if (bid == 0 && t == 0) *flag = isf;
  if (bid < 1024) {
    split_body(x, Xs, bid * 256 + t, isf, 1);
  } else if (bid < 1152) {
    split_body(W1, W1s, (bid - 1024) * 256 + t, isf, 2);
  } else if (bid < 2176) {
    int u = (bid - 1152) * 256 + t;           // 512*512 (o,i)
    int o = u >> 9, i = u & 511;
    u32* d = (u32*)(w2f8 + (size_t)o * 16384 + i * 32);
    if (isf) {
      const float4* f0 = (const float4*)((const float*)c2 + ((size_t)o * 512 + i) * 16);
      const float4* f1 = (const float4*)((const float*)c2 + (size_t)512 * 512 * 16 + ((size_t)o * 512 + i) * 16);
      #pragma unroll
      for (int j = 0; j < 4; ++j) { float4 v = f0[j]; d[j]   = packfp8x4(v.x*SCALE_C, v.y*SCALE_C, v.z*SCALE_C, v.w*SCALE_C); }
      #pragma unroll
      for (int j = 0; j < 4; ++j) { float4 v = f1[j]; d[4+j] = packfp8x4(v.x*SCALE_C, v.y*SCALE_C, v.z*SCALE_C, v.w*SCALE_C); }
    } else {
      const u16* s0 = (const u16*)c2 + ((size_t)o * 512 + i) * 16;
      const u16* s1 = (const u16*)c2 + (size_t)512 * 512 * 16 + ((size_t)o * 512 + i) * 16;
      #pragma unroll
      for (int j = 0; j < 4; ++j) d[j]   = packfp8x4(bf2f(s0[4*j])*SCALE_C, bf2f(s0[4*j+1])*SCALE_C, bf2f(s0[4*j+2])*SCALE_C, bf2f(s0[4*j+3])*SCALE_C);
      #pragma unroll
      for (int j = 0; j < 4; ++j) d[4+j] = packfp8x4(bf2f(s1[4*j])*SCALE_C, bf2f(s1[4*j+1])*SCALE_C, bf2f(s1[4*j+2])*SCALE_C, bf2f(s1[4*j+3])*SCALE_C);
    }
  } else {
    int u = (bid - 2176) * 256 + t;           // 256*512 (o,i)
    int o = u >> 9, i = u & 511;
    u32* d = (u32*)(w3f8 + (size_t)o * 8192 + i * 16);
    if (isf) {
      const float4* f0 = (const float4*)((const float*)c3 + ((size_t)o * 512 + i) * 8);
      const float4* f1 = (const float4*)((const float*)c3 + (size_t)256 * 512 * 8 + ((size_t)o * 512 + i) * 8);
      #pragma unroll
      for (int j = 0; j < 2; ++j) { float4 v = f0[j]; d[j]   = packfp8x4(v.x*SCALE_C, v.y*SCALE_C, v.z*SCALE_C, v.w*SCALE_C); }
      #pragma unroll
      for (int j = 0; j < 2; ++j) { float4 v = f1[j]; d[2+j] = packfp8x4(v.x*SCALE_C, v.y*SCALE_C, v.z*SCALE_C, v.w*SCALE_C); }
    } else {
      const u16* s0 = (const u16*)c3 + ((size_t)o * 512 + i) * 8;
      const u16* s1 = (const u16*)c3 + (size_t)256 * 512 * 8 + ((size_t)o * 512 + i) * 8;
      #pragma unroll
      for (int j = 0; j < 2; ++j) d[j]   = packfp8x4(bf2f(s0[4*j])*SCALE_C, bf2f(s0[4*j+1])*SCALE_C, bf2f(s0[4*j+2])*SCALE_C, bf2f(s0[4*j+3])*SCALE_C);
      #pragma unroll
      for (int j = 0; j < 2; ++j) d[2+j] = packfp8x4(bf2f(s1[4*j])*SCALE_C, bf2f(s1[4*j+1])*SCALE_C, bf2f(s1[4*j+2])*SCALE_C, bf2f(s1[4*j+3])*SCALE_C);
    }
  }
}

// ---------------------------------------------------------------------------
// Kernel 1: h = x @ W1^T + b1 via split-bf16 (K=768), fp32 out + sum/sumsq.
// ---------------------------------------------------------------------------
#define L1_LD 136
__global__ __launch_bounds__(256) void l1_kernel(
    const u16* __restrict__ xs, const u16* __restrict__ w1s, const void* __restrict__ b1,
    const int* __restrict__ flag, float* __restrict__ H, float2* __restrict__ PT)
{
  __shared__ u16 sA[128 * L1_LD];
  __shared__ u16 sB[64 * L1_LD];
  __shared__ float redbuf[8];
  const int n0 = blockIdx.x * 128, o0 = blockIdx.y * 64;
  const int t = threadIdx.x, wave = t >> 6, lane = t & 63, quad = lane >> 4, l16 = lane & 15;
  const int isf = *flag;
  f32x4 acc[2][4] = {};
  for (int ks = 0; ks < 768; ks += 128) {
    #pragma unroll
    for (int r = 0; r < 8; ++r) {
      int idx = t + r * 256;
      int row = idx >> 4, col = idx & 15;
      const uint4* src = (const uint4*)(xs + (size_t)(n0 + row) * 768 + ks) + col;
      *(uint4*)&sA[row * L1_LD + col * 8] = *src;
    }
    #pragma unroll
    for (int r = 0; r < 4; ++r) {
      int idx = t + r * 256;
      int row = idx >> 4, col = idx & 15;
      const uint4* src = (const uint4*)(w1s + (size_t)(o0 + row) * 768 + ks) + col;
      *(uint4*)&sB[row * L1_LD + col * 8] = *src;
    }
    __syncthreads();
    #pragma unroll
    for (int kk = 0; kk < 128; kk += 32) {
      bf16x8 bfr[4];
      #pragma unroll
      for (int fo = 0; fo < 4; ++fo)
        bfr[fo] = *(const bf16x8*)&sB[(fo * 16 + l16) * L1_LD + kk + quad * 8];
      #pragma unroll
      for (int fm = 0; fm < 2; ++fm) {
        bf16x8 av = *(const bf16x8*)&sA[(wave * 32 + fm * 16 + l16) * L1_LD + kk + quad * 8];
        #pragma unroll
        for (int fo = 0; fo < 4; ++fo)
          acc[fm][fo] = __builtin_amdgcn_mfma_f32_16x16x32_bf16(av, bfr[fo], acc[fm][fo], 0, 0, 0);
      }
    }
    __syncthreads();
  }
  float s = 0.f, sq = 0.f;
  #pragma unroll
  for (int fm = 0; fm < 2; ++fm)
  #pragma unroll
  for (int fo = 0; fo < 4; ++fo) {
    int o = o0 + fo * 16 + l16;
    float bias = inval(b1, o, isf);
    #pragma unroll
    for (int r = 0; r < 4; ++r) {
      int n = n0 + wave * 32 + fm * 16 + quad * 4 + r;
      float h = acc[fm][fo][r] + bias;
      H[(size_t)n * 512 + o] = h;
      s += h; sq += h * h;
    }
  }
  #pragma unroll
  for (int off = 32; off; off >>= 1) { s += __shfl_down(s, off); sq += __shfl_down(sq, off); }
  if (lane == 0) { redbuf[wave] = s; redbuf[4 + wave] = sq; }
  __syncthreads();
  if (t == 0) {
    float S = redbuf[0] + redbuf[1] + redbuf[2] + redbuf[3];
    float Q = redbuf[4] + redbuf[5] + redbuf[6] + redbuf[7];
    PT[blockIdx.y * 32 + blockIdx.x] = make_float2(S, Q);
  }
}

// ---------------------------------------------------------------------------
// Kernel 3: BN+ReLU+basis + FP8 MFMA GEMM, templated o-tile width OT.
// OT=256 halves trig duplication (needs kz=6, 48MB partials); OT=128 is the
// proven r10 config (kz=5). BN stats fused. 4 i/step.
// LDS: OT=128 -> 27.6KB (5/CU); OT=256 -> 46KB (3/CU).
// ---------------------------------------------------------------------------
#define K2_LDB 144
template <int OT>
__global__ __launch_bounds__(256) void kan2_kernel(
    const float* __restrict__ H, const unsigned char* __restrict__ w2f8,
    const void* __restrict__ gammap, const void* __restrict__ betap,
    const int* __restrict__ flag, const float2* __restrict__ PT,
    float* __restrict__ P, int kzT)
{
  constexpr int FO = OT / 32;          // fo count per wave-pair (4 or 8)
  constexpr int BP = OT / 32;          // B-stage row-iters (4 or 8)
  __shared__ unsigned char sA8[64 * K2_LDB];
  __shared__ unsigned char sB8[OT * K2_LDB];
  __shared__ float sred[8];
  const int n0 = blockIdx.x * 64, o0 = blockIdx.y * OT, kz = blockIdx.z;
  const int t = threadIdx.x, wave = t >> 6, lane = t & 63, quad = lane >> 4, l16 = lane & 15;
  const int wm = (wave & 1) * 32, wo = (wave >> 1) * (OT / 2);
  const int isf = *flag;
  {
    float2 p = PT[t];
    float s = p.x, q = p.y;
    #pragma unroll
    for (int off = 32; off; off >>= 1) { s += __shfl_down(s, off); q += __shfl_down(q, off); }
    if (lane == 0) { sred[wave] = s; sred[4 + wave] = q; }
  }
  __syncthreads();
  const float Ssum = sred[0] + sred[1] + sred[2] + sred[3];
  const float Qsum = sred[4] + sred[5] + sred[6] + sred[7];
  const float Nn = 4096.f * 512.f;
  const float mean = Ssum / Nn;
  const float rstd = rsqrtf(Qsum / Nn - mean * mean + 1e-5f);
  const float gs = inval(gammap, 0, isf) * rstd;
  const float beta = inval(betap, 0, isf);
  const int am = t >> 2, ai = t & 3;
  const int q = 128 / kzT, rr = 128 % kzT;
  const int nst = q + (kz < rr ? 1 : 0);
  const int i0 = (kz * q + (kz < rr ? kz : rr)) * 4;
  const int r0 = t >> 3, seg = t & 7;
  const unsigned char* bsrc = w2f8 + (size_t)(o0 + r0) * 16384 + (size_t)i0 * 32 + seg * 16;
  const float* hsrc = H + (size_t)(n0 + am) * 512 + i0 + ai;
  f32x4 acc[2][FO] = {};
  float ph = *hsrc;
  for (int s = 0; s < nst; ++s) {
    #pragma unroll
    for (int p = 0; p < BP; ++p) {
      uint4 v = *(const uint4*)(bsrc + (size_t)p * 32 * 16384);
      *(uint4*)&sB8[(r0 + 32 * p) * K2_LDB + seg * 16] = v;
    }
    {
      float a = fmaxf((ph - mean) * gs + beta, 0.f);
      float s1, c1; __sincosf(a, &s1, &c1);
      float t2 = c1 + c1;
      float cg[16], sg[16];
      cg[0] = c1; sg[0] = s1;
      cg[1] = fmaf(t2, c1, -1.f); sg[1] = t2 * s1;
      #pragma unroll
      for (int g = 2; g < 16; ++g) {
        cg[g] = fmaf(t2, cg[g-1], -cg[g-2]);
        sg[g] = fmaf(t2, sg[g-1], -sg[g-2]);
      }
      u32 pk[8];
      #pragma unroll
      for (int j = 0; j < 4; ++j) pk[j]   = packfp8x4(cg[4*j], cg[4*j+1], cg[4*j+2], cg[4*j+3]);
      #pragma unroll
      for (int j = 0; j < 4; ++j) pk[4+j] = packfp8x4(sg[4*j], sg[4*j+1], sg[4*j+2], sg[4*j+3]);
      uint4* dst = (uint4*)&sA8[am * K2_LDB + ai * 32];
      dst[0] = *(uint4*)&pk[0]; dst[1] = *(uint4*)&pk[4];
    }
    __syncthreads();
    bsrc += 128; hsrc += 4;
    if (s + 1 < nst) ph = *hsrc;
    #pragma unroll
    for (int kk = 0; kk < 128; kk += 32) {
      i64 bfr[FO], afr[2];
      #pragma unroll
      for (int fo = 0; fo < FO; ++fo)
        bfr[fo] = *(const i64*)&sB8[(wo + fo * 16 + l16) * K2_LDB + kk + quad * 8];
      #pragma unroll
      for (int fm = 0; fm < 2; ++fm)
        afr[fm] = *(const i64*)&sA8[(wm + fm * 16 + l16) * K2_LDB + kk + quad * 8];
      #pragma unroll
      for (int fm = 0; fm < 2; ++fm)
      #pragma unroll
      for (int fo = 0; fo < FO; ++fo)
        acc[fm][fo] = __builtin_amdgcn_mfma_f32_16x16x32_fp8_fp8(afr[fm], bfr[fo], acc[fm][fo], 0, 0, 0);
    }
    __syncthreads();
  }
  float* Pk = P + (size_t)kz * (4096 * 512);
  #pragma unroll
  for (int fm = 0; fm < 2; ++fm)
  #pragma unroll
  for (int fo = 0; fo < FO; ++fo) {
    int o = o0 + wo + fo * 16 + l16;
    #pragma unroll
    for (int r = 0; r < 4; ++r) {
      int n = n0 + wm + fm * 16 + quad * 4 + r;
      Pk[(size_t)n * 512 + o] = acc[fm][fo][r] * INV_SCALE;
    }
  }
}

// ---------------------------------------------------------------------------
// Kernel 4: basis (grid=8) + FP8 MFMA GEMM, 256-o tile (no oy dup), kz=6.
// reduce2 fused (each partial-set read once now). Tile 32n x 256o.
// Grid (128,1,6) = 768 -> 3/CU. LDS 41472 B.
// ---------------------------------------------------------------------------
#define K3_LDB 144
__global__ __launch_bounds__(256) void kan3_kernel(
    const float* __restrict__ P2, const void* __restrict__ bias2,
    const unsigned char* __restrict__ w3f8,
    const int* __restrict__ flag, float* __restrict__ Q, int kzT2)
{
  __shared__ unsigned char sA8[32 * K3_LDB];
  __shared__ unsigned char sB8[256 * K3_LDB];
  const int n0 = blockIdx.x * 32, kz = blockIdx.z;
  const int t = threadIdx.x, wave = t >> 6, lane = t & 63, quad = lane >> 4, l16 = lane & 15;
  const int wo = wave * 64;
  const int am = t >> 3, ai = t & 7;
  const int nst = 10 + (kz < 4 ? 1 : 0);
  const int i0 = (kz * 10 + (kz < 4 ? kz : 4)) * 8;
  const int r0 = t >> 3, seg = t & 7;
  const int isf = *flag;
  const unsigned char* bsrc = w3f8 + (size_t)r0 * 8192 + (size_t)i0 * 16 + seg * 16;
  const float* psrc = P2 + (size_t)(n0 + am) * 512 + i0 + ai;
  f32x4 acc[2][4] = {};
  float ph;
  {
    float v = inval(bias2, i0 + ai, isf);
    for (int k = 0; k < kzT2; ++k) v += psrc[(size_t)k * 4096 * 512];
    ph = v;
  }
  for (int s = 0; s < nst; ++s) {
    #pragma unroll
    for (int p = 0; p < 8; ++p) {
      uint4 v = *(const uint4*)(bsrc + (size_t)p * 32 * 8192);
      *(uint4*)&sB8[(r0 + 32 * p) * K3_LDB + seg * 16] = v;
    }
    {
      float s1, c1; __sincosf(ph, &s1, &c1);
      float t2 = c1 + c1;
      float cg[8], sg[8];
      cg[0] = c1; sg[0] = s1;
      cg[1] = fmaf(t2, c1, -1.f); sg[1] = t2 * s1;
      #pragma unroll
      for (int g = 2; g < 8; ++g) {
        cg[g] = fmaf(t2, cg[g-1], -cg[g-2]);
        sg[g] = fmaf(t2, sg[g-1], -sg[g-2]);
      }
      u32 pk[4];
      pk[0] = packfp8x4(cg[0], cg[1], cg[2], cg[3]);
      pk[1] = packfp8x4(cg[4], cg[5], cg[6], cg[7]);
      pk[2] = packfp8x4(sg[0], sg[1], sg[2], sg[3]);
      pk[3] = packfp8x4(sg[4], sg[5], sg[6], sg[7]);
      *(uint4*)&sA8[am * K3_LDB + ai * 16] = *(uint4*)&pk[0];
    }
    __syncthreads();
    bsrc += 128; psrc += 8;
    if (s + 1 < nst) {
      float v = inval(bias2, i0 + (s + 1) * 8 + ai, isf);
      for (int k = 0; k < kzT2; ++k) v += psrc[(size_t)k * 4096 * 512];
      ph = v;
    }
    #pragma unroll
    for (int kk = 0; kk < 128; kk += 32) {
      i64 bfr[4], afr[2];
      #pragma unroll
      for (int fo = 0; fo < 4; ++fo)
        bfr[fo] = *(const i64*)&sB8[(wo + fo * 16 + l16) * K3_LDB + kk + quad * 8];
      #pragma unroll
      for (int fm = 0; fm < 2; ++fm)
        afr[fm] = *(const i64*)&sA8[(fm * 16 + l16) * K3_LDB + kk + quad * 8];
      #pragma unroll
      for (int fm = 0; fm < 2; ++fm)
      #pragma unroll
      for (int fo = 0; fo < 4; ++fo)
        acc[fm][fo] = __builtin_amdgcn_mfma_f32_16x16x32_fp8_fp8(afr[fm], bfr[fo], acc[fm][fo], 0, 0, 0);
    }
    __syncthreads();
  }
  float* Qk = Q + (size_t)kz * (4096 * 256);
  #pragma unroll
  for (int fm = 0; fm < 2; ++fm)
  #pragma unroll
  for (int fo = 0; fo < 4; ++fo) {
    int o = wo + fo * 16 + l16;
    #pragma unroll
    for (int r = 0; r < 4; ++r) {
      int n = n0 + fm * 16 + quad * 4 + r;
      Qk[(size_t)n * 256 + o] = acc[fm][fo][r] * INV_SCALE;
    }
  }
}

// ---------------------------------------------------------------------------
// Kernel 5: fused 6-partial reduce + bias3 + row softmax + fp32 store.
// ---------------------------------------------------------------------------
__global__ __launch_bounds__(256) void softmax_kernel(
    const float* __restrict__ Q, const void* __restrict__ bias3,
    const int* __restrict__ flag, float* __restrict__ out)
{
  const int t = threadIdx.x, wave = t >> 6, lane = t & 63;
  const int row = blockIdx.x * 4 + wave;
  const int isf = *flag;
  size_t base = (size_t)row * 256 + lane * 4;
  float v0 = 0.f, v1 = 0.f, v2 = 0.f, v3 = 0.f;
  #pragma unroll
  for (int k = 0; k < 6; ++k) {
    float4 a = *(const float4*)(Q + (size_t)k * 4096 * 256 + base);
    v0 += a.x; v1 += a.y; v2 += a.z; v3 += a.w;
  }
  int o = lane * 4;
  v0 += inval(bias3, o + 0, isf);
  v1 += inval(bias3, o + 1, isf);
  v2 += inval(bias3, o + 2, isf);
  v3 += inval(bias3, o + 3, isf);
  float m = fmaxf(fmaxf(v0, v1), fmaxf(v2, v3));
  #pragma unroll
  for (int off = 32; off; off >>= 1) m = fmaxf(m, __shfl_xor(m, off));
  float e0 = __expf(v0 - m), e1 = __expf(v1 - m), e2 = __expf(v2 - m), e3 = __expf(v3 - m);
  float s = e0 + e1 + e2 + e3;
  #pragma unroll
  for (int off = 32; off; off >>= 1) s += __shfl_xor(s, off);
  float inv = 1.f / s;
  *(float4*)(out + base) = make_float4(e0 * inv, e1 * inv, e2 * inv, e3 * inv);
}

// ---------------------------------------------------------------------------
extern "C" void kernel_launch(void* const* d_in, const int* in_sizes, int n_in,
                              void* d_out, int out_size, void* d_ws, size_t ws_size,
                              hipStream_t stream)
{
  const void* x     = d_in[0];
  const void* W1    = d_in[1];
  const void* b1    = d_in[2];
  const void* gamma = d_in[3];
  const void* beta  = d_in[4];
  const void* c2    = d_in[5];
  const void* bias2 = d_in[6];
  const void* c3    = d_in[7];
  const void* bias3 = d_in[8];

  // kan2 config: 256-o tile (half trig dup) needs kz=6 -> 48MB partials.
  const bool wide2 = (ws_size >= (83ull << 20));
  const int kz2 = wide2 ? 6 : ((ws_size >= (75ull << 20)) ? 5 : 3);

  char* ws = (char*)d_ws;
  float*          H    = (float*)(ws + 0);
  unsigned char*  W2F8 = (unsigned char*)(ws + (16ull << 20));
  unsigned char*  W3F8 = (unsigned char*)(ws + (24ull << 20));
  u16*            Xs   = (u16*)(ws + (26ull << 20));
  u16*            W1s  = (u16*)(ws + (33ull << 20));
  float*          P2   = (float*)(ws + (34ull << 20));
  float*          Q3   = (float*)(ws + 0);
  size_t tail = (34ull << 20) + (size_t)kz2 * (8ull << 20) + 524288;
  float2* PT   = (float2*)(ws + tail);
  int*    FLAG = (int*)   (ws + tail + 65536);

  prep_all_kernel<<<dim3(2688), dim3(256), 0, stream>>>(x, W1, Xs, W1s, c2, W2F8, c3, W3F8, FLAG);
  l1_kernel   <<<dim3(32, 8), dim3(256), 0, stream>>>(Xs, W1s, b1, FLAG, H, PT);
  if (wide2)
    kan2_kernel<256><<<dim3(64, 2, kz2), dim3(256), 0, stream>>>(H, W2F8, gamma, beta, FLAG, PT, P2, kz2);
  else
    kan2_kernel<128><<<dim3(64, 4, kz2), dim3(256), 0, stream>>>(H, W2F8, gamma, beta, FLAG, PT, P2, kz2);
  kan3_kernel <<<dim3(128, 1, 6), dim3(256), 0, stream>>>(P2, bias2, W3F8, FLAG, Q3, kz2);
  softmax_kernel<<<dim3(1024), dim3(256), 0, stream>>>(Q3, bias3, FLAG, (float*)d_out);
}